// Round 10
// baseline (953.849 us; speedup 1.0000x reference)
//
#include <hip/hip_runtime.h>
#include <cstdint>
#include <cstddef>

#define NB 8
#define NS 1024
#define NE 512
#define NH 8
#define ND 64
#define NL 6
#define NHF 2048
#define NROW (NB*NS)   // 8192

typedef __bf16 bf16_t;
typedef __bf16 bf8v __attribute__((ext_vector_type(8)));
typedef __bf16 bf4v __attribute__((ext_vector_type(4)));
typedef float  f4   __attribute__((ext_vector_type(4)));

extern "C" __device__ float __ocml_native_exp2_f32(float);
#define EXP2F __ocml_native_exp2_f32
#define LOG2E 1.4426950408889634f

// ---- async global->LDS, 16B per lane (LDS dest = wave-uniform base + lane*16) ----
__device__ __forceinline__ void async_copy16(const bf16_t* g, bf16_t* l) {
    __builtin_amdgcn_global_load_lds(
        (const __attribute__((address_space(1))) void*)g,
        (__attribute__((address_space(3))) void*)l,
        16, 0, 0);
}

// gelu(x) = x * sigmoid(2*0.7978845608*(x+0.044715x^3)); exp2-domain, v_rcp.
__device__ __forceinline__ float gelu_f(float x) {
    const float s = fmaf(0.044715f * x * x, x, x);
    const float e = EXP2F(-2.3022081995f * s);   // 2*0.7978845608*log2(e)
    return x * __builtin_amdgcn_rcpf(1.0f + e);
}

// ---------------------------------------------------------------------------
// Core bf16 GEMM (128xBN, m97-structure): C[M,N] = A[M,K]*B[N,K]^T.
// OUT: 1 = bf16 row-major (swapped mfma -> 8B stores)
//      2 = bf16 in-place residual RMW (swapped)
// BN=128 (32 MFMA/wave/barrier, 64KB LDS, 2 blocks/CU). Used for FFN2.
// NOTE (r8 post-mortem): cross-block LN fusion with device-scope
// __threadfence was a 4x loss (L2 writeback storm). GEMM and LN stay split.
// ---------------------------------------------------------------------------
template<int BN, int ACT, int OUT>
__device__ __forceinline__ void gemm_core(
    bf16_t* __restrict__ sm,
    const bf16_t* __restrict__ A, const bf16_t* __restrict__ Bm,
    const float* __restrict__ bias, bf16_t* __restrict__ Cb,
    int m0, int n0, int N, int K)
{
    constexpr int JN = BN / 32, WSPAN = BN / 2;
    bf16_t* As = sm;             // 2 x 8192
    bf16_t* Bs = sm + 2*128*64;  // 2 x (BN*64)
    const int tid  = threadIdx.x;
    const int lane = tid & 63;
    const int wave = tid >> 6;
    const int wm = wave >> 1, wn = wave & 1;
    const int quad = lane >> 4, l16 = lane & 15;
    const int srow = tid >> 3;                         // 0..31
    const int scol = (((tid & 7) ^ (srow & 7)) << 3);  // swizzled source col

    f4 acc[4][JN] = {};

    const bf16_t* Ag = A  + (size_t)(m0 + srow) * K + scol;
    const bf16_t* Bg = Bm + (size_t)(n0 + srow) * K + scol;
    const int sw = (l16 & 7);

    auto stage = [&](int buf, int kt) {
#pragma unroll
        for (int r = 0; r < 4; ++r)
            async_copy16(Ag + (size_t)r * 32 * K + kt, As + buf*8192 + tid*8 + r*2048);
#pragma unroll
        for (int r = 0; r < BN/32; ++r)
            async_copy16(Bg + (size_t)r * 32 * K + kt, Bs + buf*(BN*64) + tid*8 + r*2048);
    };

    stage(0, 0);
    int buf = 0;
    for (int kt = 0; kt < K; kt += 64, buf ^= 1) {
        __syncthreads();                       // drains buf's loads; frees buf^1
        if (kt + 64 < K) stage(buf ^ 1, kt + 64);
        const bf16_t* Ab = As + buf*8192;
        const bf16_t* Bb = Bs + buf*(BN*64);
#pragma unroll
        for (int s = 0; s < 2; ++s) {
            const int c8 = ((s*4 + quad) ^ sw) * 8;
            bf8v af[4], bfv[JN];
#pragma unroll
            for (int i = 0; i < 4; ++i)
                af[i] = *(const bf8v*)(Ab + (wm*64 + i*16 + l16)*64 + c8);
#pragma unroll
            for (int j = 0; j < JN; ++j)
                bfv[j] = *(const bf8v*)(Bb + (wn*WSPAN + j*16 + l16)*64 + c8);
#pragma unroll
            for (int i = 0; i < 4; ++i)
#pragma unroll
                for (int j = 0; j < JN; ++j)
                    acc[i][j] = __builtin_amdgcn_mfma_f32_16x16x32_bf16(bfv[j], af[i], acc[i][j], 0, 0, 0);
        }
    }

    // swapped layout: m = ...+l16, n = ...+quad*4+r (4 consecutive n/lane)
#pragma unroll
    for (int i = 0; i < 4; ++i) {
        const int mi = m0 + wm*64 + i*16 + l16;
        const size_t m = (size_t)mi;
#pragma unroll
        for (int j = 0; j < JN; ++j) {
            const int nb = n0 + wn*WSPAN + j*16 + quad*4;
            const f4 bv = *(const f4*)(bias + nb);
            f4 v = acc[i][j] + bv;
            if (ACT) {
#pragma unroll
                for (int r = 0; r < 4; ++r) v[r] = gelu_f(v[r]);
            }
            bf4v* cp = (bf4v*)(Cb + m * (size_t)N + nb);
            bf4v o;
            if (OUT == 2) {
                const bf4v old = *cp;
#pragma unroll
                for (int r = 0; r < 4; ++r) o[r] = (bf16_t)((float)old[r] + v[r]);
            } else {
#pragma unroll
                for (int r = 0; r < 4; ++r) o[r] = (bf16_t)v[r];
            }
            *cp = o;
        }
    }
}

// 1-D launcher with XCD-chunk swizzle (T1): nwg%8==0; XCD j owns a
// contiguous logical range -> operand-panel reuse in its private L2.
template<int BN, int ACT, int OUT>
__global__ __launch_bounds__(256)
void gemm_bt_k(const bf16_t* __restrict__ A, const bf16_t* __restrict__ Bm,
               const float* __restrict__ bias, bf16_t* __restrict__ Cb,
               int N, int K, int nxb)
{
    __shared__ __align__(16) bf16_t smem[2*128*64 + 2*BN*64];
    const int d = blockIdx.x, q = gridDim.x >> 3;
    const int L = (d & 7) * q + (d >> 3);
    gemm_core<BN, ACT, OUT>(smem, A, Bm, bias, Cb,
                            (L % nxb) * 128, (L / nxb) * BN, N, K);
}

// ---------------------------------------------------------------------------
// Fused residual-RMW + LayerNorm GEMM:  xb = LN(xb + A*B^T + bias) (per row).
// O-PROJ ONLY (K=512): intra-block fusion (block owns whole rows).
// Tile: 32 rows x 512 cols; 512 thr; grid 256 = 1/CU.
// ---------------------------------------------------------------------------
__global__ __launch_bounds__(512, 2)
void gemm_rmw_ln_k(const bf16_t* __restrict__ A, const bf16_t* __restrict__ Bm,
                   const float* __restrict__ bias, bf16_t* __restrict__ xb,
                   const float* __restrict__ gamma, const float* __restrict__ beta,
                   float* __restrict__ fout, int wf, int K)
{
    __shared__ __align__(16) bf16_t As[2*32*64];     // 8 KB
    __shared__ __align__(16) bf16_t Bs[2*512*64];    // 128 KB
    __shared__ float wsum[8][32], wssq[8][32];
    const int tid  = threadIdx.x;          // 0..511
    const int lane = tid & 63;
    const int wave = tid >> 6;             // 0..7 ; wave owns cols wave*64..+63
    const int quad = lane >> 4, l16 = lane & 15;
    const int sw = l16 & 7;
    const int srow = tid >> 3;             // 0..63
    const int scol = ((tid & 7) ^ (srow & 7)) << 3;
    const int m0 = blockIdx.x * 32;

    const bf16_t* Ag = A  + (size_t)(m0 + srow) * K + scol;   // rows 0..31 (tid<256)
    const bf16_t* Bg = Bm + (size_t)srow * K + scol;          // + r*64 rows

    f4 acc[2][4] = {};

    auto stage = [&](int buf, int kt) {
        if (tid < 256)                                   // wave-uniform (4 waves)
            async_copy16(Ag + kt, As + buf*2048 + tid*8);
#pragma unroll
        for (int r = 0; r < 8; ++r)
            async_copy16(Bg + (size_t)r * 64 * K + kt, Bs + buf*32768 + (r*512 + tid)*8);
    };

    stage(0, 0);
    int buf = 0;
    for (int kt = 0; kt < K; kt += 64, buf ^= 1) {
        __syncthreads();                   // drains buf's loads; frees buf^1
        if (kt + 64 < K) stage(buf ^ 1, kt + 64);
        const bf16_t* Ab = As + buf*2048;
        const bf16_t* Bb = Bs + buf*32768;
#pragma unroll
        for (int s = 0; s < 2; ++s) {
            const int c8 = ((s*4 + quad) ^ sw) * 8;
            bf8v af[2], bfv[4];
#pragma unroll
            for (int i = 0; i < 2; ++i)
                af[i] = *(const bf8v*)(Ab + (i*16 + l16)*64 + c8);
#pragma unroll
            for (int j = 0; j < 4; ++j)
                bfv[j] = *(const bf8v*)(Bb + (wave*64 + j*16 + l16)*64 + c8);
#pragma unroll
            for (int i = 0; i < 2; ++i)
#pragma unroll
                for (int j = 0; j < 4; ++j)
                    acc[i][j] = __builtin_amdgcn_mfma_f32_16x16x32_bf16(bfv[j], af[i], acc[i][j], 0, 0, 0);
        }
    }

    // ---- epilogue: residual RMW, row stats, LN, store ----
    // swapped layout: row = i*16+l16, col = wave*64 + j*16 + quad*4 + r
    f4 v[2][4];
    float ps[2], pss[2];
#pragma unroll
    for (int i = 0; i < 2; ++i) {
        ps[i] = 0.f; pss[i] = 0.f;
        const size_t m = (size_t)(m0 + i*16 + l16);
#pragma unroll
        for (int j = 0; j < 4; ++j) {
            const int nb = wave*64 + j*16 + quad*4;
            const f4 bv = *(const f4*)(bias + nb);
            const bf4v old = *(const bf4v*)(xb + m * NE + nb);
            f4 t = acc[i][j] + bv;
#pragma unroll
            for (int r = 0; r < 4; ++r) {
                t[r] += (float)old[r];
                ps[i]  += t[r];
                pss[i] += t[r] * t[r];
            }
            v[i][j] = t;
        }
        // reduce across the 4 quads (lanes sharing l16)
        ps[i]  += __shfl_xor(ps[i], 16, 64);
        ps[i]  += __shfl_xor(ps[i], 32, 64);
        pss[i] += __shfl_xor(pss[i], 16, 64);
        pss[i] += __shfl_xor(pss[i], 32, 64);
    }
    if (quad == 0) {
#pragma unroll
        for (int i = 0; i < 2; ++i) {
            wsum[wave][i*16 + l16] = ps[i];
            wssq[wave][i*16 + l16] = pss[i];
        }
    }
    __syncthreads();
#pragma unroll
    for (int i = 0; i < 2; ++i) {
        const int row = i*16 + l16;
        float s = 0.f, ss = 0.f;
#pragma unroll
        for (int w = 0; w < 8; ++w) { s += wsum[w][row]; ss += wssq[w][row]; }
        const float mean = s * (1.0f / NE);
        const float var  = ss * (1.0f / NE) - mean * mean;
        const float inv  = rsqrtf(var + 1e-5f);
        const size_t m = (size_t)(m0 + row);
#pragma unroll
        for (int j = 0; j < 4; ++j) {
            const int nb = wave*64 + j*16 + quad*4;
            const f4 gm = *(const f4*)(gamma + nb);
            const f4 bt = *(const f4*)(beta + nb);
            f4 o;
            bf4v ob;
#pragma unroll
            for (int r = 0; r < 4; ++r) {
                o[r]  = gm[r] * ((v[i][j][r] - mean) * inv) + bt[r];
                ob[r] = (bf16_t)o[r];
            }
            *(bf4v*)(xb + m * NE + nb) = ob;
            if (wf) *(f4*)(fout + m * NE + nb) = o;
        }
    }
}

// ---------------------------------------------------------------------------
// Truly fused QKV: ONE block computes Q, K and V for a 128m x 64n tile.
// 1-D grid 512, XCD swizzle: XCD j owns all 64 m-blocks of n-panel j ->
// its 192 KB {wq,wk,wv} panel is fetched once into that XCD's L2.
// ---------------------------------------------------------------------------
__global__ __launch_bounds__(256, 2)
void gemm_qkv_k(const bf16_t* __restrict__ A,
                const bf16_t* __restrict__ wq, const bf16_t* __restrict__ wk, const bf16_t* __restrict__ wv,
                const float* __restrict__ bq, const float* __restrict__ bk, const float* __restrict__ bv,
                bf16_t* __restrict__ Q, bf16_t* __restrict__ K, bf16_t* __restrict__ Vt,
                const unsigned short* __restrict__ rank)
{
    __shared__ __align__(16) bf16_t As_[2*128*64];      // 32 KB, dbuf
    __shared__ __align__(16) bf16_t Bs_[3][2*64*64];    // 48 KB, dbuf x {Q,K,V}
    const int tid  = threadIdx.x;
    const int lane = tid & 63;
    const int wave = tid >> 6;
    const int wm = wave >> 1, wn = wave & 1;
    const int quad = lane >> 4, l16 = lane & 15;
    const int sw = l16 & 7;
    const int srow = tid >> 3;                         // 0..31
    const int scol = (((tid & 7) ^ (srow & 7)) << 3);  // swizzled source col
    const int d = blockIdx.x;
    const int L = (d & 7) * 64 + (d >> 3);             // bijective, 512%8==0
    const int m0 = (L & 63) * 128, n0 = (L >> 6) * 64;

    const bf16_t* Ag = A + (size_t)(m0 + srow) * NE + scol;
    const bf16_t* Wg0 = wq + (size_t)(n0 + srow) * NE + scol;
    const bf16_t* Wg1 = wk + (size_t)(n0 + srow) * NE + scol;
    const bf16_t* Wg2 = wv + (size_t)(n0 + srow) * NE + scol;

    f4 acc[3][4][2] = {};

    auto stage = [&](int buf, int kt) {
#pragma unroll
        for (int r = 0; r < 4; ++r)
            async_copy16(Ag + (size_t)r*32*NE + kt, As_ + buf*8192 + tid*8 + r*2048);
#pragma unroll
        for (int r = 0; r < 2; ++r) {
            async_copy16(Wg0 + (size_t)r*32*NE + kt, Bs_[0] + buf*4096 + tid*8 + r*2048);
            async_copy16(Wg1 + (size_t)r*32*NE + kt, Bs_[1] + buf*4096 + tid*8 + r*2048);
            async_copy16(Wg2 + (size_t)r*32*NE + kt, Bs_[2] + buf*4096 + tid*8 + r*2048);
        }
    };

    stage(0, 0);
    int buf = 0;
    for (int kt = 0; kt < NE; kt += 64, buf ^= 1) {
        __syncthreads();
        if (kt + 64 < NE) stage(buf ^ 1, kt + 64);
        const bf16_t* Ab = As_ + buf*8192;
#pragma unroll
        for (int s = 0; s < 2; ++s) {
            const int c8 = ((s*4 + quad) ^ sw) * 8;
            bf8v af[4];
#pragma unroll
            for (int i = 0; i < 4; ++i)
                af[i] = *(const bf8v*)(Ab + (wm*64 + i*16 + l16)*64 + c8);
#pragma unroll
            for (int mat = 0; mat < 3; ++mat) {
                const bf16_t* Bb = Bs_[mat] + buf*4096;
                const bf8v b0 = *(const bf8v*)(Bb + (wn*32      + l16)*64 + c8);
                const bf8v b1 = *(const bf8v*)(Bb + (wn*32 + 16 + l16)*64 + c8);
                if (mat < 2) {
#pragma unroll
                    for (int i = 0; i < 4; ++i) {
                        acc[mat][i][0] = __builtin_amdgcn_mfma_f32_16x16x32_bf16(b0, af[i], acc[mat][i][0], 0, 0, 0);
                        acc[mat][i][1] = __builtin_amdgcn_mfma_f32_16x16x32_bf16(b1, af[i], acc[mat][i][1], 0, 0, 0);
                    }
                } else {   // V: natural order for the scatter epilogue layout
#pragma unroll
                    for (int i = 0; i < 4; ++i) {
                        acc[2][i][0] = __builtin_amdgcn_mfma_f32_16x16x32_bf16(af[i], b0, acc[2][i][0], 0, 0, 0);
                        acc[2][i][1] = __builtin_amdgcn_mfma_f32_16x16x32_bf16(af[i], b1, acc[2][i][1], 0, 0, 0);
                    }
                }
            }
        }
    }

    // Q (row-major) + K (rank-packed rows): swapped layout, 8B stores.
#pragma unroll
    for (int i = 0; i < 4; ++i) {
        const int mi = m0 + wm*64 + i*16 + l16;
        const int mk = (mi & ~1023) + (int)rank[mi];
#pragma unroll
        for (int j = 0; j < 2; ++j) {
            const int nb = n0 + wn*32 + j*16 + quad*4;
            const f4 vq = acc[0][i][j] + *(const f4*)(bq + nb);
            const f4 vk = acc[1][i][j] + *(const f4*)(bk + nb);
            bf4v oq, ok;
#pragma unroll
            for (int r = 0; r < 4; ++r) { oq[r] = (bf16_t)vq[r]; ok[r] = (bf16_t)vk[r]; }
            *(bf4v*)(Q + (size_t)mi * NE + nb) = oq;
            *(bf4v*)(K + (size_t)mk * NE + nb) = ok;
        }
    }
    // V: natural layout (m = ...+quad*4+r, n = ...+l16), packed column scatter.
#pragma unroll
    for (int j = 0; j < 2; ++j) {
        const int n = n0 + wn*32 + j*16 + l16;
        const float bvv = bv[n];
#pragma unroll
        for (int i = 0; i < 4; ++i) {
            const int mbase = m0 + wm*64 + i*16 + quad*4;
            const size_t b8h = (size_t)((mbase >> 10)*8 + (n >> 6));
            bf16_t* rowp = Vt + (b8h*64 + (size_t)(n & 63))*1024;
#pragma unroll
            for (int r = 0; r < 4; ++r)
                rowp[rank[mbase + r]] = (bf16_t)(acc[2][i][j][r] + bvv);
        }
    }
}

// ---------------------------------------------------------------------------
// 256x256 8-phase GEMM (T2+T3+T4+T5) -- FFN1 only (grid 256 = 1/CU).
// 1-D grid + XCD swizzle: XCD j owns the 32 m-blocks of n-panel j.
// ---------------------------------------------------------------------------
template<int ACT, int OUT>
__device__ __forceinline__ void gemm256_core(
    bf16_t* __restrict__ sm,
    const bf16_t* __restrict__ A, const bf16_t* __restrict__ Bm,
    const float* __restrict__ bias, bf16_t* __restrict__ Cb,
    int m0, int n0, int N, int K)
{
    const int tid  = threadIdx.x;          // 0..511
    const int lane = tid & 63;
    const int wave = tid >> 6;             // 0..7
    const int wm = wave >> 2, wn = wave & 3;
    const int quad = lane >> 4, l16 = lane & 15;
    const int sw = l16 & 7;
    const int srow = tid >> 3;             // 0..63
    const int scol = ((tid & 7) ^ (srow & 7)) << 3;

    bf16_t* As = sm;                 // [dbuf][half][128][64]
    bf16_t* Bs = sm + 4 * 8192;

    const bf16_t* Ag = A  + (size_t)(m0 + srow) * K + scol;
    const bf16_t* Bg = Bm + (size_t)(n0 + srow) * K + scol;

    auto stageA = [&](int d, int h, int kt) {
        bf16_t* dst = As + (d*2 + h) * 8192 + tid * 8;
        const bf16_t* src = Ag + (size_t)(h * 128) * K + kt;
        async_copy16(src, dst);
        async_copy16(src + (size_t)64 * K, dst + 4096);
    };
    auto stageB = [&](int d, int h, int kt) {
        bf16_t* dst = Bs + (d*2 + h) * 8192 + tid * 8;
        const bf16_t* src = Bg + (size_t)(h * 128) * K + kt;
        async_copy16(src, dst);
        async_copy16(src + (size_t)64 * K, dst + 4096);
    };

    const int nt = K >> 6;

    f4 acc[8][4] = {};
    bf8v bfr[4][2], al[4][2], ah[4][2];

    auto mfmaQ = [&](const bf8v (&af)[4][2], int fb, int gb) {
#pragma unroll
        for (int kh = 0; kh < 2; ++kh)
#pragma unroll
            for (int f = 0; f < 4; ++f)
#pragma unroll
                for (int g = 0; g < 2; ++g)
                    acc[fb+f][gb+g] = __builtin_amdgcn_mfma_f32_16x16x32_bf16(bfr[gb+g][kh], af[f][kh], acc[fb+f][gb+g], 0, 0, 0);
    };

    stageB(0, 0, 0);  stageB(0, 1, 0);  stageA(0, 0, 0);  stageA(0, 1, 0);
    stageB(1, 0, 64); stageB(1, 1, 64); stageA(1, 0, 64);
    asm volatile("s_waitcnt vmcnt(6)" ::: "memory");
    __builtin_amdgcn_s_barrier();

    for (int t = 0; t < nt; ++t) {
        const int d = t & 1;
        const int kt2 = (t + 2) << 6;
        const bf16_t* Ab = As + (d*2 + wm) * 8192;
        const bf16_t* Bb = Bs + (d*2 + (wn >> 1)) * 8192 + (wn & 1) * 4096;

        // P1: all-B + A-low; stage A1(t+1)
#pragma unroll
        for (int g = 0; g < 4; ++g)
#pragma unroll
            for (int kh = 0; kh < 2; ++kh)
                bfr[g][kh] = *(const bf8v*)(Bb + (g*16 + l16)*64 + (((kh*4 + quad) ^ sw) << 3));
#pragma unroll
        for (int f = 0; f < 4; ++f)
#pragma unroll
            for (int kh = 0; kh < 2; ++kh)
                al[f][kh] = *(const bf8v*)(Ab + (f*16 + l16)*64 + (((kh*4 + quad) ^ sw) << 3));
        if (t + 1 < nt) stageA(d ^ 1, 1, (t + 1) << 6);
        __builtin_amdgcn_s_barrier();
        __builtin_amdgcn_s_setprio(1);
        mfmaQ(al, 0, 0);
        __builtin_amdgcn_s_setprio(0);
        asm volatile("s_waitcnt lgkmcnt(0)" ::: "memory");
        __builtin_amdgcn_s_barrier();

        // P2: A-high; stage B0(t+2)
#pragma unroll
        for (int f = 0; f < 4; ++f)
#pragma unroll
            for (int kh = 0; kh < 2; ++kh)
                ah[f][kh] = *(const bf8v*)(Ab + ((f + 4)*16 + l16)*64 + (((kh*4 + quad) ^ sw) << 3));
        if (t + 2 < nt) stageB(d, 0, kt2);
        __builtin_amdgcn_s_barrier();
        __builtin_amdgcn_s_setprio(1);
        mfmaQ(ah, 4, 0);
        __builtin_amdgcn_s_setprio(0);
        asm volatile("s_waitcnt lgkmcnt(0)" ::: "memory");
        __builtin_amdgcn_s_barrier();

        // P3: stage B1(t+2)
        if (t + 2 < nt) stageB(d, 1, kt2);
        __builtin_amdgcn_s_barrier();
        __builtin_amdgcn_s_setprio(1);
        mfmaQ(al, 0, 2);
        __builtin_amdgcn_s_setprio(0);
        asm volatile("s_waitcnt lgkmcnt(0)" ::: "memory");
        __builtin_amdgcn_s_barrier();

        // P4: stage A0(t+2); counted vmcnt
        if (t + 2 < nt) stageA(d, 0, kt2);
        __builtin_amdgcn_s_barrier();
        __builtin_amdgcn_s_setprio(1);
        mfmaQ(ah, 4, 2);
        __builtin_amdgcn_s_setprio(0);
        asm volatile("s_waitcnt lgkmcnt(0)" ::: "memory");
        if (t + 1 < nt) {
            if (t + 2 < nt) asm volatile("s_waitcnt vmcnt(6)" ::: "memory");
            else            asm volatile("s_waitcnt vmcnt(0)" ::: "memory");
        }
        __builtin_amdgcn_s_barrier();
    }

    // swapped layout: m = ...+l16, n = ...+quad*4+r
#pragma unroll
    for (int f = 0; f < 8; ++f) {
        const int mi = m0 + wm*128 + f*16 + l16;
        const size_t m = (size_t)mi;
#pragma unroll
        for (int g = 0; g < 4; ++g) {
            const int nb = n0 + wn*64 + g*16 + quad*4;
            const f4 bv = *(const f4*)(bias + nb);
            f4 v = acc[f][g] + bv;
            if (ACT) {
#pragma unroll
                for (int r = 0; r < 4; ++r) v[r] = gelu_f(v[r]);
            }
            bf4v* cp = (bf4v*)(Cb + m * (size_t)N + nb);
            bf4v o;
            if (OUT == 2) {
                const bf4v old = *cp;
#pragma unroll
                for (int r = 0; r < 4; ++r) o[r] = (bf16_t)((float)old[r] + v[r]);
            } else {
#pragma unroll
                for (int r = 0; r < 4; ++r) o[r] = (bf16_t)v[r];
            }
            *cp = o;
        }
    }
}

template<int ACT, int OUT>
__global__ __launch_bounds__(512, 2)
void gemm256_k(const bf16_t* __restrict__ A, const bf16_t* __restrict__ Bm,
               const float* __restrict__ bias, bf16_t* __restrict__ Cb, int N, int K)
{
    __shared__ __align__(16) bf16_t smem[8 * 8192];   // 128 KiB
    const int d = blockIdx.x;
    const int L = (d & 7) * 32 + (d >> 3);            // bijective, 256%8==0
    gemm256_core<ACT, OUT>(smem, A, Bm, bias, Cb,
                           (L & 31) * 256, (L >> 5) * 256, N, K);
}

// ---------------------------------------------------------------------------
// Flash attention over PACKED keys (exact; masked keys skipped).
// 4 waves x 32 q-rows; K-tile = 64 keys, double-buffered; 48KB LDS -> 3/CU.
// 1-D grid 512, XCD swizzle groups the 8 q-blocks of 8 consecutive bh on
// one XCD (K/V panel ~128KB reused 8x from that XCD's L2).
// ---------------------------------------------------------------------------
__global__ __launch_bounds__(256)
void attn_k(const bf16_t* __restrict__ Q, const bf16_t* __restrict__ Kg,
            const bf16_t* __restrict__ Vt, const float* __restrict__ maskf,
            const int* __restrict__ cntpad, bf16_t* __restrict__ O)
{
    __shared__ __align__(16) bf16_t Ks[2][64*64];  // [key][d]  swizzled
    __shared__ __align__(16) bf16_t Vs[2][64*64];  // [d][key]  swizzled
    __shared__ __align__(16) bf16_t Ps[4][32*64];  // per-wave P, swizzled
    const int tid  = threadIdx.x;
    const int lane = tid & 63;
    const int wave = tid >> 6;
    const int quad = lane >> 4, l16 = lane & 15;
    const int sw = l16 & 7;
    const int dd = blockIdx.x, tt = dd >> 3;
    const int L = 8 * (dd & 7) + (tt & 7) + 64 * (tt >> 3);  // bijective
    const int bh = L & 63;
    const int b = bh >> 3, h = bh & 7;
    const int q0 = (L >> 6) * 128;
    const int kend = cntpad[b];

    bf8v qf[2][2];
#pragma unroll
    for (int qi = 0; qi < 2; ++qi) {
        const bf16_t* Qp = Q + (size_t)(b*NS + q0 + wave*32 + qi*16 + l16) * NE + h*ND;
        qf[qi][0] = *(const bf8v*)(Qp + quad*8);
        qf[qi][1] = *(const bf8v*)(Qp + 32 + quad*8);
    }

    f4 oacc[2][4] = {};
    float rs[2] = {0.f, 0.f};

    const int srow = tid >> 3;
    const int scol = (((tid & 7) ^ (srow & 7)) << 3);
    const float c1 = 0.125f * LOG2E;

    auto stage = [&](int buf, int kt) {
#pragma unroll
        for (int r = 0; r < 2; ++r) {
            async_copy16(Kg + (size_t)(b*NS + kt + r*32 + srow) * NE + h*ND + scol,
                         Ks[buf] + (r*256 + tid) * 8);
            async_copy16(Vt + (size_t)(bh*ND + r*32 + srow) * NS + kt + scol,
                         Vs[buf] + (r*256 + tid) * 8);
        }
    };

    stage(0, 0);
    int buf = 0;
    for (int kt = 0; kt < kend; kt += 64, buf ^= 1) {
        __syncthreads();
        if (kt + 64 < kend) stage(buf ^ 1, kt + 64);

        // S = Q*K^T (swapped): sacc[qi][j][r] = S[q=...+l16][key=j*16+quad*4+r]
        f4 sacc[2][4] = {};
        __builtin_amdgcn_s_setprio(1);
#pragma unroll
        for (int j = 0; j < 4; ++j) {
            bf8v kf0 = *(const bf8v*)(Ks[buf] + (j*16 + l16)*64 + ((quad    ) ^ sw)*8);
            bf8v kf1 = *(const bf8v*)(Ks[buf] + (j*16 + l16)*64 + ((quad + 4) ^ sw)*8);
#pragma unroll
            for (int qi = 0; qi < 2; ++qi) {
                sacc[qi][j] = __builtin_amdgcn_mfma_f32_16x16x32_bf16(kf0, qf[qi][0], sacc[qi][j], 0, 0, 0);
                sacc[qi][j] = __builtin_amdgcn_mfma_f32_16x16x32_bf16(kf1, qf[qi][1], sacc[qi][j], 0, 0, 0);
            }
        }
        __builtin_amdgcn_s_setprio(0);

        // P = exp2(S*c1 + mask); packed 8B writes to per-wave LDS (A-layout)
        bf16_t* Pw = Ps[wave];
#pragma unroll
        for (int j = 0; j < 4; ++j) {
            const f4 mkv = *(const f4*)(maskf + b*NS + kt + j*16 + quad*4);
#pragma unroll
            for (int qi = 0; qi < 2; ++qi) {
                bf4v o;
#pragma unroll
                for (int r = 0; r < 4; ++r) {
                    const float p = EXP2F(fmaf(sacc[qi][j][r], c1, mkv[r]));
                    rs[qi] += p;
                    o[r] = (bf16_t)p;
                }
                const int row = qi*16 + l16;
                const int chunk = (j*2 + (quad >> 1)) ^ sw;
                *(bf4v*)(Pw + row*64 + chunk*8 + (quad & 1)*4) = o;
            }
        }

        // O += P*V (swapped): oacc[qi][nt][r] = O[q=l16][d=nt*16+quad*4+r]
        __builtin_amdgcn_s_setprio(1);
#pragma unroll
        for (int ks = 0; ks < 2; ++ks) {
            bf8v pf[2];
#pragma unroll
            for (int qi = 0; qi < 2; ++qi)
                pf[qi] = *(const bf8v*)(Pw + (qi*16 + l16)*64 + ((ks*4 + quad) ^ sw)*8);
#pragma unroll
            for (int nt = 0; nt < 4; ++nt) {
                bf8v vf = *(const bf8v*)(Vs[buf] + (nt*16 + l16)*64 + ((ks*4 + quad) ^ sw)*8);
#pragma unroll
                for (int qi = 0; qi < 2; ++qi)
                    oacc[qi][nt] = __builtin_amdgcn_mfma_f32_16x16x32_bf16(vf, pf[qi], oacc[qi][nt], 0, 0, 0);
            }
        }
        __builtin_amdgcn_s_setprio(0);
    }

    // reduce row sums across quads (scalar per lane), scale, packed stores
#pragma unroll
    for (int qi = 0; qi < 2; ++qi) {
        float s = rs[qi];
        s += __shfl_xor(s, 16, 64);
        s += __shfl_xor(s, 32, 64);
        const float inv = 1.0f / s;
        const size_t row = (size_t)(b*NS + q0 + wave*32 + qi*16 + l16);
#pragma unroll
        for (int nt = 0; nt < 4; ++nt) {
            bf4v o;
#pragma unroll
            for (int r = 0; r < 4; ++r) o[r] = (bf16_t)(oacc[qi][nt][r] * inv);
            *(bf4v*)(O + row * NE + h*ND + nt*16 + quad*4) = o;
        }
    }
}

// ---------------------------------------------------------------------------
// In-place LayerNorm over the bf16 residual stream (after FFN2).
// 16 rows/block (4 waves x 4 rows), bf8v 16B loads/stores; grid 512.
// ---------------------------------------------------------------------------
__global__ __launch_bounds__(256)
void ln_k(bf16_t* __restrict__ xb,
          const float* __restrict__ gamma, const float* __restrict__ beta,
          float* __restrict__ fout, int wf)
{
    const int wave = threadIdx.x >> 6, lane = threadIdx.x & 63;
    const f4 g0 = *(const f4*)(gamma + lane*8);
    const f4 g1 = *(const f4*)(gamma + lane*8 + 4);
    const f4 b0 = *(const f4*)(beta  + lane*8);
    const f4 b1 = *(const f4*)(beta  + lane*8 + 4);
#pragma unroll
    for (int rr = 0; rr < 4; ++rr) {
        const size_t row  = (size_t)blockIdx.x * 16 + wave * 4 + rr;
        const size_t base = row * NE;
        const bf8v v = *(const bf8v*)(xb + base + lane*8);
        float xv[8], s = 0.f, ss = 0.f;
#pragma unroll
        for (int r = 0; r < 8; ++r) { xv[r] = (float)v[r]; s += xv[r]; ss += xv[r]*xv[r]; }
#pragma unroll
        for (int off = 32; off > 0; off >>= 1) {
            s  += __shfl_xor(s,  off, 64);
            ss += __shfl_xor(ss, off, 64);
        }
        const float mean = s * (1.0f / NE);
        const float var  = ss * (1.0f / NE) - mean * mean;
        const float inv  = rsqrtf(var + 1e-5f);
        f4 o0, o1;
        bf8v ob;
#pragma unroll
        for (int r = 0; r < 4; ++r) {
            o0[r] = g0[r] * ((xv[r]     - mean) * inv) + b0[r];
            o1[r] = g1[r] * ((xv[r + 4] - mean) * inv) + b1[r];
            ob[r]     = (bf16_t)o0[r];
            ob[r + 4] = (bf16_t)o1[r];
        }
        *(bf8v*)(xb + base + lane*8) = ob;
        if (wf) {
            *(f4*)(fout + base + lane*8)     = o0;
            *(f4*)(fout + base + lane*8 + 4) = o1;
        }
    }
}

// ---------------------------------------------------------------------------
// One-shot fp32->bf16 conversion of all 6 weight tensors + x, WITH mask
// packing fused in (8 extra blocks; pack runs in wave 0 of each) -- one
// fewer dispatch in the graph.
// ---------------------------------------------------------------------------
#define W4SZ ((size_t)NL*NE*NE/4)     // float4s per E x E weight set
#define WBSZ ((size_t)NL*NE*NHF/4)    // float4s per E x HF weight set
#define XSZ  ((size_t)NROW*NE/4)      // float4s for x
#define CVT_TOTAL (4*W4SZ + 2*WBSZ + XSZ)
#define CVT_BLOCKS ((unsigned)((CVT_TOTAL + 255) / 256))

__global__ void cvt_pack_k(const float* __restrict__ wq, const float* __restrict__ wk,
                           const float* __restrict__ wv, const float* __restrict__ wo,
                           const float* __restrict__ w1, const float* __restrict__ w2,
                           const float* __restrict__ x,
                           bf16_t* __restrict__ owq, bf16_t* __restrict__ owk,
                           bf16_t* __restrict__ owv, bf16_t* __restrict__ owo,
                           bf16_t* __restrict__ ow1, bf16_t* __restrict__ ow2,
                           bf16_t* __restrict__ ox,
                           const int* __restrict__ m, unsigned short* __restrict__ rank,
                           int* __restrict__ cntpad, float* __restrict__ maskp)
{
    if (blockIdx.x >= CVT_BLOCKS) {
        // ---- mask packing: one block per batch, wave 0 only ----
        if (threadIdx.x >= 64) return;
        const int b = blockIdx.x - CVT_BLOCKS, lane = threadIdx.x;
        unsigned long long bals[16];
        int cnt = 0;
#pragma unroll
        for (int c = 0; c < 16; ++c) {
            const bool mk = m[b*NS + c*64 + lane] != 0;
            bals[c] = __ballot(mk);
            cnt += __popcll(bals[c]);
        }
        int u = 0, kk = 0;
#pragma unroll
        for (int c = 0; c < 16; ++c) {
            const unsigned long long bal = bals[c];
            const bool mk = (bal >> lane) & 1;
            const int pu = __popcll(bal & ((1ull << lane) - 1));
            const int r = mk ? (u + pu) : (cnt + kk + (lane - pu));
            rank[b*NS + c*64 + lane] = (unsigned short)r;
            const int cb = __popcll(bal);
            u += cb; kk += 64 - cb;
        }
        if (lane == 0) {
            int cp = (cnt + 63) & ~63;
            cntpad[b] = cp < 64 ? 64 : cp;
        }
#pragma unroll
        for (int c = 0; c < 16; ++c) {
            const int j = c*64 + lane;
            maskp[b*NS + j] = (j < cnt) ? 0.0f : -1.0e6f * LOG2E;
        }
        return;
    }
    size_t i = (size_t)blockIdx.x * 256 + threadIdx.x;
    if (i >= CVT_TOTAL) return;
    const float* src; bf16_t* dst;
    if      (i < 1*W4SZ)           { src = wq; dst = owq; }
    else if (i < 2*W4SZ)           { src = wk; dst = owk; i -= 1*W4SZ; }
    else if (i < 3*W4SZ)           { src = wv; dst = owv; i -= 2*W4SZ; }
    else if (i < 4*W4SZ)           { src = wo; dst = owo; i -= 3*W4SZ; }
    else if (i < 4*W4SZ + WBSZ)    { src = w1; dst = ow1; i -= 4*W4SZ; }
    else if (i < 4*W4SZ + 2*WBSZ)  { src = w2; dst = ow2; i -= 4*W4SZ + WBSZ; }
    else                           { src = x;  dst = ox;  i -= 4*W4SZ + 2*WBSZ; }
    const f4 v = ((const f4*)src)[i];
    bf4v o;
    o[0] = (bf16_t)v[0]; o[1] = (bf16_t)v[1]; o[2] = (bf16_t)v[2]; o[3] = (bf16_t)v[3];
    ((bf4v*)dst)[i] = o;
}

// ---------------------------------------------------------------------------
extern "C" void kernel_launch(void* const* d_in, const int* in_sizes, int n_in,
                              void* d_out, int out_size, void* d_ws, size_t ws_size,
                              hipStream_t stream)
{
    (void)in_sizes; (void)n_in; (void)out_size; (void)ws_size;
    const float* x   = (const float*)d_in[0];
    const int*   msk = (const int*)d_in[1];
    const float* WQ = (const float*)d_in[2];  const float* bQ  = (const float*)d_in[3];
    const float* WK = (const float*)d_in[4];  const float* bK  = (const float*)d_in[5];
    const float* WV = (const float*)d_in[6];  const float* bV  = (const float*)d_in[7];
    const float* WO = (const float*)d_in[8];  const float* bO  = (const float*)d_in[9];
    const float* W1 = (const float*)d_in[10]; const float* b1  = (const float*)d_in[11];
    const float* W2 = (const float*)d_in[12]; const float* b2  = (const float*)d_in[13];
    const float* g1 = (const float*)d_in[14]; const float* bt1 = (const float*)d_in[15];
    const float* g2 = (const float*)d_in[16]; const float* bt2 = (const float*)d_in[17];

    char* ws = (char*)d_ws;
    size_t off = 0;
    auto alloc = [&](size_t bytes) { char* p = ws + off; off += (bytes + 255) & ~(size_t)255; return p; };
    bf16_t* xb    = (bf16_t*)alloc((size_t)NROW*NE*2);
    bf16_t* Qb    = (bf16_t*)alloc((size_t)NROW*NE*2);
    bf16_t* Kb    = (bf16_t*)alloc((size_t)NROW*NE*2);
    bf16_t* Vtb   = (bf16_t*)alloc((size_t)NROW*NE*2);
    bf16_t* AOb   = (bf16_t*)alloc((size_t)NROW*NE*2);
    bf16_t* hb    = (bf16_t*)alloc((size_t)NROW*NHF*2);
    bf16_t* wqc   = (bf16_t*)alloc((size_t)NL*NE*NE*2);
    bf16_t* wkc   = (bf16_t*)alloc((size_t)NL*NE*NE*2);
    bf16_t* wvc   = (bf16_t*)alloc((size_t)NL*NE*NE*2);
    bf16_t* woc   = (bf16_t*)alloc((size_t)NL*NE*NE*2);
    bf16_t* w1c   = (bf16_t*)alloc((size_t)NL*NHF*NE*2);
    bf16_t* w2c   = (bf16_t*)alloc((size_t)NL*NE*NHF*2);
    float*  maskp = (float*) alloc((size_t)NB*NS*4);
    unsigned short* rankb = (unsigned short*)alloc((size_t)NB*NS*2);
    int*    cntp  = (int*)   alloc(NB*4);

    cvt_pack_k<<<dim3(CVT_BLOCKS + NB), dim3(256), 0, stream>>>(
        WQ, WK, WV, WO, W1, W2, x, wqc, wkc, wvc, woc, w1c, w2c, xb,
        msk, rankb, cntp, maskp);

    for (int l = 0; l < NL; ++l) {
        const bf16_t* wq  = wqc + (size_t)l*NE*NE;
        const bf16_t* wk  = wkc + (size_t)l*NE*NE;
        const bf16_t* wv  = wvc + (size_t)l*NE*NE;
        const bf16_t* wo  = woc + (size_t)l*NE*NE;
        const bf16_t* w1p = w1c + (size_t)l*NHF*NE;
        const bf16_t* w2p = w2c + (size_t)l*NE*NHF;
        const int last = (l == NL - 1);

        gemm_qkv_k<<<dim3(512), dim3(256), 0, stream>>>(
            xb, wq, wk, wv, bQ + l*NE, bK + l*NE, bV + l*NE, Qb, Kb, Vtb, rankb);
        attn_k<<<dim3(512), dim3(256), 0, stream>>>(Qb, Kb, Vtb, maskp, cntp, AOb);
        gemm_rmw_ln_k<<<dim3(256), dim3(512), 0, stream>>>(
            AOb, wo, bO + l*NE, xb, g1 + l*NE, bt1 + l*NE,
            nullptr, 0, NE);                              // xb = LN1(xb + O-proj)
        gemm256_k<1, 1><<<dim3(256), dim3(512), 0, stream>>>(
            xb, w1p, b1 + l*NHF, hb, NHF, NE);
        gemm_bt_k<128, 0, 2><<<dim3(256), dim3(256), 0, stream>>>(
            hb, w2p, b2 + l*NE, xb, NE, NHF, 64);         // xb += FFN2
        ln_k<<<dim3(NROW/16), dim3(256), 0, stream>>>(
            xb, g2 + l*NE, bt2 + l*NE, (float*)d_out, last);
    }
}

// Round 11
// 881.709 us; speedup vs baseline: 1.0818x; 1.0818x over previous
//
#include <hip/hip_runtime.h>
#include <cstdint>
#include <cstddef>

#define NB 8
#define NS 1024
#define NE 512
#define NH 8
#define ND 64
#define NL 6
#define NHF 2048
#define NROW (NB*NS)   // 8192

typedef __bf16 bf16_t;
typedef __bf16 bf8v __attribute__((ext_vector_type(8)));
typedef __bf16 bf4v __attribute__((ext_vector_type(4)));
typedef float  f4   __attribute__((ext_vector_type(4)));

extern "C" __device__ float __ocml_native_exp2_f32(float);
#define EXP2F __ocml_native_exp2_f32
#define LOG2E 1.4426950408889634f

// ---- async global->LDS, 16B per lane (LDS dest = wave-uniform base + lane*16) ----
__device__ __forceinline__ void async_copy16(const bf16_t* g, bf16_t* l) {
    __builtin_amdgcn_global_load_lds(
        (const __attribute__((address_space(1))) void*)g,
        (__attribute__((address_space(3))) void*)l,
        16, 0, 0);
}

// gelu(x) = x * sigmoid(2*0.7978845608*(x+0.044715x^3)); exp2-domain, v_rcp.
__device__ __forceinline__ float gelu_f(float x) {
    const float s = fmaf(0.044715f * x * x, x, x);
    const float e = EXP2F(-2.3022081995f * s);   // 2*0.7978845608*log2(e)
    return x * __builtin_amdgcn_rcpf(1.0f + e);
}

// ---------------------------------------------------------------------------
// Core bf16 GEMM (128xBN, m97-structure): C[M,N] = A[M,K]*B[N,K]^T.
// OUT: 1 = bf16 row-major (swapped mfma -> 8B stores)
//      2 = bf16 in-place residual RMW (swapped)
// BN=128 (32 MFMA/wave/barrier, 64KB LDS, 2 blocks/CU). Used for FFN2.
// NOTE (r8): cross-block LN fusion w/ device fences = 4x loss. Stay split.
// NOTE (r10): XCD-swizzled block remaps on these L3-resident tiles cost
// ~75us total -- natural 2-D grid order is faster here. Do not re-land.
// ---------------------------------------------------------------------------
template<int BN, int ACT, int OUT>
__device__ __forceinline__ void gemm_core(
    bf16_t* __restrict__ sm,
    const bf16_t* __restrict__ A, const bf16_t* __restrict__ Bm,
    const float* __restrict__ bias, bf16_t* __restrict__ Cb,
    int m0, int n0, int N, int K)
{
    constexpr int JN = BN / 32, WSPAN = BN / 2;
    bf16_t* As = sm;             // 2 x 8192
    bf16_t* Bs = sm + 2*128*64;  // 2 x (BN*64)
    const int tid  = threadIdx.x;
    const int lane = tid & 63;
    const int wave = tid >> 6;
    const int wm = wave >> 1, wn = wave & 1;
    const int quad = lane >> 4, l16 = lane & 15;
    const int srow = tid >> 3;                         // 0..31
    const int scol = (((tid & 7) ^ (srow & 7)) << 3);  // swizzled source col

    f4 acc[4][JN] = {};

    const bf16_t* Ag = A  + (size_t)(m0 + srow) * K + scol;
    const bf16_t* Bg = Bm + (size_t)(n0 + srow) * K + scol;
    const int sw = (l16 & 7);

    auto stage = [&](int buf, int kt) {
#pragma unroll
        for (int r = 0; r < 4; ++r)
            async_copy16(Ag + (size_t)r * 32 * K + kt, As + buf*8192 + tid*8 + r*2048);
#pragma unroll
        for (int r = 0; r < BN/32; ++r)
            async_copy16(Bg + (size_t)r * 32 * K + kt, Bs + buf*(BN*64) + tid*8 + r*2048);
    };

    stage(0, 0);
    int buf = 0;
    for (int kt = 0; kt < K; kt += 64, buf ^= 1) {
        __syncthreads();                       // drains buf's loads; frees buf^1
        if (kt + 64 < K) stage(buf ^ 1, kt + 64);
        const bf16_t* Ab = As + buf*8192;
        const bf16_t* Bb = Bs + buf*(BN*64);
#pragma unroll
        for (int s = 0; s < 2; ++s) {
            const int c8 = ((s*4 + quad) ^ sw) * 8;
            bf8v af[4], bfv[JN];
#pragma unroll
            for (int i = 0; i < 4; ++i)
                af[i] = *(const bf8v*)(Ab + (wm*64 + i*16 + l16)*64 + c8);
#pragma unroll
            for (int j = 0; j < JN; ++j)
                bfv[j] = *(const bf8v*)(Bb + (wn*WSPAN + j*16 + l16)*64 + c8);
#pragma unroll
            for (int i = 0; i < 4; ++i)
#pragma unroll
                for (int j = 0; j < JN; ++j)
                    acc[i][j] = __builtin_amdgcn_mfma_f32_16x16x32_bf16(bfv[j], af[i], acc[i][j], 0, 0, 0);
        }
    }

    // swapped layout: m = ...+l16, n = ...+quad*4+r (4 consecutive n/lane)
#pragma unroll
    for (int i = 0; i < 4; ++i) {
        const int mi = m0 + wm*64 + i*16 + l16;
        const size_t m = (size_t)mi;
#pragma unroll
        for (int j = 0; j < JN; ++j) {
            const int nb = n0 + wn*WSPAN + j*16 + quad*4;
            const f4 bv = *(const f4*)(bias + nb);
            f4 v = acc[i][j] + bv;
            if (ACT) {
#pragma unroll
                for (int r = 0; r < 4; ++r) v[r] = gelu_f(v[r]);
            }
            bf4v* cp = (bf4v*)(Cb + m * (size_t)N + nb);
            bf4v o;
            if (OUT == 2) {
                const bf4v old = *cp;
#pragma unroll
                for (int r = 0; r < 4; ++r) o[r] = (bf16_t)((float)old[r] + v[r]);
            } else {
#pragma unroll
                for (int r = 0; r < 4; ++r) o[r] = (bf16_t)v[r];
            }
            *cp = o;
        }
    }
}

template<int BN, int ACT, int OUT>
__global__ __launch_bounds__(256)
void gemm_bt_k(const bf16_t* __restrict__ A, const bf16_t* __restrict__ Bm,
               const float* __restrict__ bias, bf16_t* __restrict__ Cb, int N, int K)
{
    __shared__ __align__(16) bf16_t smem[2*128*64 + 2*BN*64];
    gemm_core<BN, ACT, OUT>(smem, A, Bm, bias, Cb,
                            blockIdx.x * 128, blockIdx.y * BN, N, K);
}

// ---------------------------------------------------------------------------
// Fused residual-RMW + LayerNorm GEMM:  xb = LN(xb + A*B^T + bias) (per row).
// O-PROJ ONLY (K=512): intra-block fusion (block owns whole rows).
// Tile: 32 rows x 512 cols; 512 thr; grid 256 = 1/CU.
// ---------------------------------------------------------------------------
__global__ __launch_bounds__(512, 2)
void gemm_rmw_ln_k(const bf16_t* __restrict__ A, const bf16_t* __restrict__ Bm,
                   const float* __restrict__ bias, bf16_t* __restrict__ xb,
                   const float* __restrict__ gamma, const float* __restrict__ beta,
                   float* __restrict__ fout, int wf, int K)
{
    __shared__ __align__(16) bf16_t As[2*32*64];     // 8 KB
    __shared__ __align__(16) bf16_t Bs[2*512*64];    // 128 KB
    __shared__ float wsum[8][32], wssq[8][32];
    const int tid  = threadIdx.x;          // 0..511
    const int lane = tid & 63;
    const int wave = tid >> 6;             // 0..7 ; wave owns cols wave*64..+63
    const int quad = lane >> 4, l16 = lane & 15;
    const int sw = l16 & 7;
    const int srow = tid >> 3;             // 0..63
    const int scol = ((tid & 7) ^ (srow & 7)) << 3;
    const int m0 = blockIdx.x * 32;

    const bf16_t* Ag = A  + (size_t)(m0 + srow) * K + scol;   // rows 0..31 (tid<256)
    const bf16_t* Bg = Bm + (size_t)srow * K + scol;          // + r*64 rows

    f4 acc[2][4] = {};

    auto stage = [&](int buf, int kt) {
        if (tid < 256)                                   // wave-uniform (4 waves)
            async_copy16(Ag + kt, As + buf*2048 + tid*8);
#pragma unroll
        for (int r = 0; r < 8; ++r)
            async_copy16(Bg + (size_t)r * 64 * K + kt, Bs + buf*32768 + (r*512 + tid)*8);
    };

    stage(0, 0);
    int buf = 0;
    for (int kt = 0; kt < K; kt += 64, buf ^= 1) {
        __syncthreads();                   // drains buf's loads; frees buf^1
        if (kt + 64 < K) stage(buf ^ 1, kt + 64);
        const bf16_t* Ab = As + buf*2048;
        const bf16_t* Bb = Bs + buf*32768;
#pragma unroll
        for (int s = 0; s < 2; ++s) {
            const int c8 = ((s*4 + quad) ^ sw) * 8;
            bf8v af[2], bfv[4];
#pragma unroll
            for (int i = 0; i < 2; ++i)
                af[i] = *(const bf8v*)(Ab + (i*16 + l16)*64 + c8);
#pragma unroll
            for (int j = 0; j < 4; ++j)
                bfv[j] = *(const bf8v*)(Bb + (wave*64 + j*16 + l16)*64 + c8);
#pragma unroll
            for (int i = 0; i < 2; ++i)
#pragma unroll
                for (int j = 0; j < 4; ++j)
                    acc[i][j] = __builtin_amdgcn_mfma_f32_16x16x32_bf16(bfv[j], af[i], acc[i][j], 0, 0, 0);
        }
    }

    // ---- epilogue: residual RMW, row stats, LN, store ----
    // swapped layout: row = i*16+l16, col = wave*64 + j*16 + quad*4 + r
    f4 v[2][4];
    float ps[2], pss[2];
#pragma unroll
    for (int i = 0; i < 2; ++i) {
        ps[i] = 0.f; pss[i] = 0.f;
        const size_t m = (size_t)(m0 + i*16 + l16);
#pragma unroll
        for (int j = 0; j < 4; ++j) {
            const int nb = wave*64 + j*16 + quad*4;
            const f4 bv = *(const f4*)(bias + nb);
            const bf4v old = *(const bf4v*)(xb + m * NE + nb);
            f4 t = acc[i][j] + bv;
#pragma unroll
            for (int r = 0; r < 4; ++r) {
                t[r] += (float)old[r];
                ps[i]  += t[r];
                pss[i] += t[r] * t[r];
            }
            v[i][j] = t;
        }
        // reduce across the 4 quads (lanes sharing l16)
        ps[i]  += __shfl_xor(ps[i], 16, 64);
        ps[i]  += __shfl_xor(ps[i], 32, 64);
        pss[i] += __shfl_xor(pss[i], 16, 64);
        pss[i] += __shfl_xor(pss[i], 32, 64);
    }
    if (quad == 0) {
#pragma unroll
        for (int i = 0; i < 2; ++i) {
            wsum[wave][i*16 + l16] = ps[i];
            wssq[wave][i*16 + l16] = pss[i];
        }
    }
    __syncthreads();
#pragma unroll
    for (int i = 0; i < 2; ++i) {
        const int row = i*16 + l16;
        float s = 0.f, ss = 0.f;
#pragma unroll
        for (int w = 0; w < 8; ++w) { s += wsum[w][row]; ss += wssq[w][row]; }
        const float mean = s * (1.0f / NE);
        const float var  = ss * (1.0f / NE) - mean * mean;
        const float inv  = rsqrtf(var + 1e-5f);
        const size_t m = (size_t)(m0 + row);
#pragma unroll
        for (int j = 0; j < 4; ++j) {
            const int nb = wave*64 + j*16 + quad*4;
            const f4 gm = *(const f4*)(gamma + nb);
            const f4 bt = *(const f4*)(beta + nb);
            f4 o;
            bf4v ob;
#pragma unroll
            for (int r = 0; r < 4; ++r) {
                o[r]  = gm[r] * ((v[i][j][r] - mean) * inv) + bt[r];
                ob[r] = (bf16_t)o[r];
            }
            *(bf4v*)(xb + m * NE + nb) = ob;
            if (wf) *(f4*)(fout + m * NE + nb) = o;
        }
    }
}

// ---------------------------------------------------------------------------
// Truly fused QKV: ONE block computes Q, K and V for a 128m x 64n tile,
// staging the shared A (x) tile ONCE per K-iter plus three 64-row B tiles.
// grid (64,8) = 512 blocks = 2/CU (LDS 80 KB).
// ---------------------------------------------------------------------------
__global__ __launch_bounds__(256, 2)
void gemm_qkv_k(const bf16_t* __restrict__ A,
                const bf16_t* __restrict__ wq, const bf16_t* __restrict__ wk, const bf16_t* __restrict__ wv,
                const float* __restrict__ bq, const float* __restrict__ bk, const float* __restrict__ bv,
                bf16_t* __restrict__ Q, bf16_t* __restrict__ K, bf16_t* __restrict__ Vt,
                const unsigned short* __restrict__ rank)
{
    __shared__ __align__(16) bf16_t As_[2*128*64];      // 32 KB, dbuf
    __shared__ __align__(16) bf16_t Bs_[3][2*64*64];    // 48 KB, dbuf x {Q,K,V}
    const int tid  = threadIdx.x;
    const int lane = tid & 63;
    const int wave = tid >> 6;
    const int wm = wave >> 1, wn = wave & 1;
    const int quad = lane >> 4, l16 = lane & 15;
    const int sw = l16 & 7;
    const int srow = tid >> 3;                         // 0..31
    const int scol = (((tid & 7) ^ (srow & 7)) << 3);  // swizzled source col
    const int m0 = blockIdx.x * 128, n0 = blockIdx.y * 64;

    const bf16_t* Ag = A + (size_t)(m0 + srow) * NE + scol;
    const bf16_t* Wg0 = wq + (size_t)(n0 + srow) * NE + scol;
    const bf16_t* Wg1 = wk + (size_t)(n0 + srow) * NE + scol;
    const bf16_t* Wg2 = wv + (size_t)(n0 + srow) * NE + scol;

    f4 acc[3][4][2] = {};

    auto stage = [&](int buf, int kt) {
#pragma unroll
        for (int r = 0; r < 4; ++r)
            async_copy16(Ag + (size_t)r*32*NE + kt, As_ + buf*8192 + tid*8 + r*2048);
#pragma unroll
        for (int r = 0; r < 2; ++r) {
            async_copy16(Wg0 + (size_t)r*32*NE + kt, Bs_[0] + buf*4096 + tid*8 + r*2048);
            async_copy16(Wg1 + (size_t)r*32*NE + kt, Bs_[1] + buf*4096 + tid*8 + r*2048);
            async_copy16(Wg2 + (size_t)r*32*NE + kt, Bs_[2] + buf*4096 + tid*8 + r*2048);
        }
    };

    stage(0, 0);
    int buf = 0;
    for (int kt = 0; kt < NE; kt += 64, buf ^= 1) {
        __syncthreads();
        if (kt + 64 < NE) stage(buf ^ 1, kt + 64);
        const bf16_t* Ab = As_ + buf*8192;
#pragma unroll
        for (int s = 0; s < 2; ++s) {
            const int c8 = ((s*4 + quad) ^ sw) * 8;
            bf8v af[4];
#pragma unroll
            for (int i = 0; i < 4; ++i)
                af[i] = *(const bf8v*)(Ab + (wm*64 + i*16 + l16)*64 + c8);
#pragma unroll
            for (int mat = 0; mat < 3; ++mat) {
                const bf16_t* Bb = Bs_[mat] + buf*4096;
                const bf8v b0 = *(const bf8v*)(Bb + (wn*32      + l16)*64 + c8);
                const bf8v b1 = *(const bf8v*)(Bb + (wn*32 + 16 + l16)*64 + c8);
                if (mat < 2) {
#pragma unroll
                    for (int i = 0; i < 4; ++i) {
                        acc[mat][i][0] = __builtin_amdgcn_mfma_f32_16x16x32_bf16(b0, af[i], acc[mat][i][0], 0, 0, 0);
                        acc[mat][i][1] = __builtin_amdgcn_mfma_f32_16x16x32_bf16(b1, af[i], acc[mat][i][1], 0, 0, 0);
                    }
                } else {   // V: natural order for the scatter epilogue layout
#pragma unroll
                    for (int i = 0; i < 4; ++i) {
                        acc[2][i][0] = __builtin_amdgcn_mfma_f32_16x16x32_bf16(af[i], b0, acc[2][i][0], 0, 0, 0);
                        acc[2][i][1] = __builtin_amdgcn_mfma_f32_16x16x32_bf16(af[i], b1, acc[2][i][1], 0, 0, 0);
                    }
                }
            }
        }
    }

    // Q (row-major) + K (rank-packed rows): swapped layout, 8B stores.
#pragma unroll
    for (int i = 0; i < 4; ++i) {
        const int mi = m0 + wm*64 + i*16 + l16;
        const int mk = (mi & ~1023) + (int)rank[mi];
#pragma unroll
        for (int j = 0; j < 2; ++j) {
            const int nb = n0 + wn*32 + j*16 + quad*4;
            const f4 vq = acc[0][i][j] + *(const f4*)(bq + nb);
            const f4 vk = acc[1][i][j] + *(const f4*)(bk + nb);
            bf4v oq, ok;
#pragma unroll
            for (int r = 0; r < 4; ++r) { oq[r] = (bf16_t)vq[r]; ok[r] = (bf16_t)vk[r]; }
            *(bf4v*)(Q + (size_t)mi * NE + nb) = oq;
            *(bf4v*)(K + (size_t)mk * NE + nb) = ok;
        }
    }
    // V: natural layout (m = ...+quad*4+r, n = ...+l16), packed column scatter.
#pragma unroll
    for (int j = 0; j < 2; ++j) {
        const int n = n0 + wn*32 + j*16 + l16;
        const float bvv = bv[n];
#pragma unroll
        for (int i = 0; i < 4; ++i) {
            const int mbase = m0 + wm*64 + i*16 + quad*4;
            const size_t b8h = (size_t)((mbase >> 10)*8 + (n >> 6));
            bf16_t* rowp = Vt + (b8h*64 + (size_t)(n & 63))*1024;
#pragma unroll
            for (int r = 0; r < 4; ++r)
                rowp[rank[mbase + r]] = (bf16_t)(acc[2][i][j][r] + bvv);
        }
    }
}

// ---------------------------------------------------------------------------
// 256x256 8-phase GEMM (T2+T3+T4+T5) -- FFN1 only (grid 32x8 = 256 = 1/CU).
// ---------------------------------------------------------------------------
template<int ACT, int OUT>
__device__ __forceinline__ void gemm256_core(
    bf16_t* __restrict__ sm,
    const bf16_t* __restrict__ A, const bf16_t* __restrict__ Bm,
    const float* __restrict__ bias, bf16_t* __restrict__ Cb,
    int m0, int n0, int N, int K)
{
    const int tid  = threadIdx.x;          // 0..511
    const int lane = tid & 63;
    const int wave = tid >> 6;             // 0..7
    const int wm = wave >> 2, wn = wave & 3;
    const int quad = lane >> 4, l16 = lane & 15;
    const int sw = l16 & 7;
    const int srow = tid >> 3;             // 0..63
    const int scol = ((tid & 7) ^ (srow & 7)) << 3;

    bf16_t* As = sm;                 // [dbuf][half][128][64]
    bf16_t* Bs = sm + 4 * 8192;

    const bf16_t* Ag = A  + (size_t)(m0 + srow) * K + scol;
    const bf16_t* Bg = Bm + (size_t)(n0 + srow) * K + scol;

    auto stageA = [&](int d, int h, int kt) {
        bf16_t* dst = As + (d*2 + h) * 8192 + tid * 8;
        const bf16_t* src = Ag + (size_t)(h * 128) * K + kt;
        async_copy16(src, dst);
        async_copy16(src + (size_t)64 * K, dst + 4096);
    };
    auto stageB = [&](int d, int h, int kt) {
        bf16_t* dst = Bs + (d*2 + h) * 8192 + tid * 8;
        const bf16_t* src = Bg + (size_t)(h * 128) * K + kt;
        async_copy16(src, dst);
        async_copy16(src + (size_t)64 * K, dst + 4096);
    };

    const int nt = K >> 6;

    f4 acc[8][4] = {};
    bf8v bfr[4][2], al[4][2], ah[4][2];

    auto mfmaQ = [&](const bf8v (&af)[4][2], int fb, int gb) {
#pragma unroll
        for (int kh = 0; kh < 2; ++kh)
#pragma unroll
            for (int f = 0; f < 4; ++f)
#pragma unroll
                for (int g = 0; g < 2; ++g)
                    acc[fb+f][gb+g] = __builtin_amdgcn_mfma_f32_16x16x32_bf16(bfr[gb+g][kh], af[f][kh], acc[fb+f][gb+g], 0, 0, 0);
    };

    stageB(0, 0, 0);  stageB(0, 1, 0);  stageA(0, 0, 0);  stageA(0, 1, 0);
    stageB(1, 0, 64); stageB(1, 1, 64); stageA(1, 0, 64);
    asm volatile("s_waitcnt vmcnt(6)" ::: "memory");
    __builtin_amdgcn_s_barrier();

    for (int t = 0; t < nt; ++t) {
        const int d = t & 1;
        const int kt2 = (t + 2) << 6;
        const bf16_t* Ab = As + (d*2 + wm) * 8192;
        const bf16_t* Bb = Bs + (d*2 + (wn >> 1)) * 8192 + (wn & 1) * 4096;

        // P1: all-B + A-low; stage A1(t+1)
#pragma unroll
        for (int g = 0; g < 4; ++g)
#pragma unroll
            for (int kh = 0; kh < 2; ++kh)
                bfr[g][kh] = *(const bf8v*)(Bb + (g*16 + l16)*64 + (((kh*4 + quad) ^ sw) << 3));
#pragma unroll
        for (int f = 0; f < 4; ++f)
#pragma unroll
            for (int kh = 0; kh < 2; ++kh)
                al[f][kh] = *(const bf8v*)(Ab + (f*16 + l16)*64 + (((kh*4 + quad) ^ sw) << 3));
        if (t + 1 < nt) stageA(d ^ 1, 1, (t + 1) << 6);
        __builtin_amdgcn_s_barrier();
        __builtin_amdgcn_s_setprio(1);
        mfmaQ(al, 0, 0);
        __builtin_amdgcn_s_setprio(0);
        asm volatile("s_waitcnt lgkmcnt(0)" ::: "memory");
        __builtin_amdgcn_s_barrier();

        // P2: A-high; stage B0(t+2)
#pragma unroll
        for (int f = 0; f < 4; ++f)
#pragma unroll
            for (int kh = 0; kh < 2; ++kh)
                ah[f][kh] = *(const bf8v*)(Ab + ((f + 4)*16 + l16)*64 + (((kh*4 + quad) ^ sw) << 3));
        if (t + 2 < nt) stageB(d, 0, kt2);
        __builtin_amdgcn_s_barrier();
        __builtin_amdgcn_s_setprio(1);
        mfmaQ(ah, 4, 0);
        __builtin_amdgcn_s_setprio(0);
        asm volatile("s_waitcnt lgkmcnt(0)" ::: "memory");
        __builtin_amdgcn_s_barrier();

        // P3: stage B1(t+2)
        if (t + 2 < nt) stageB(d, 1, kt2);
        __builtin_amdgcn_s_barrier();
        __builtin_amdgcn_s_setprio(1);
        mfmaQ(al, 0, 2);
        __builtin_amdgcn_s_setprio(0);
        asm volatile("s_waitcnt lgkmcnt(0)" ::: "memory");
        __builtin_amdgcn_s_barrier();

        // P4: stage A0(t+2); counted vmcnt
        if (t + 2 < nt) stageA(d, 0, kt2);
        __builtin_amdgcn_s_barrier();
        __builtin_amdgcn_s_setprio(1);
        mfmaQ(ah, 4, 2);
        __builtin_amdgcn_s_setprio(0);
        asm volatile("s_waitcnt lgkmcnt(0)" ::: "memory");
        if (t + 1 < nt) {
            if (t + 2 < nt) asm volatile("s_waitcnt vmcnt(6)" ::: "memory");
            else            asm volatile("s_waitcnt vmcnt(0)" ::: "memory");
        }
        __builtin_amdgcn_s_barrier();
    }

    // swapped layout: m = ...+l16, n = ...+quad*4+r
#pragma unroll
    for (int f = 0; f < 8; ++f) {
        const int mi = m0 + wm*128 + f*16 + l16;
        const size_t m = (size_t)mi;
#pragma unroll
        for (int g = 0; g < 4; ++g) {
            const int nb = n0 + wn*64 + g*16 + quad*4;
            const f4 bv = *(const f4*)(bias + nb);
            f4 v = acc[f][g] + bv;
            if (ACT) {
#pragma unroll
                for (int r = 0; r < 4; ++r) v[r] = gelu_f(v[r]);
            }
            bf4v* cp = (bf4v*)(Cb + m * (size_t)N + nb);
            bf4v o;
            if (OUT == 2) {
                const bf4v old = *cp;
#pragma unroll
                for (int r = 0; r < 4; ++r) o[r] = (bf16_t)((float)old[r] + v[r]);
            } else {
#pragma unroll
                for (int r = 0; r < 4; ++r) o[r] = (bf16_t)v[r];
            }
            *cp = o;
        }
    }
}

template<int ACT, int OUT>
__global__ __launch_bounds__(512, 2)
void gemm256_k(const bf16_t* __restrict__ A, const bf16_t* __restrict__ Bm,
               const float* __restrict__ bias, bf16_t* __restrict__ Cb, int N, int K)
{
    __shared__ __align__(16) bf16_t smem[8 * 8192];   // 128 KiB
    gemm256_core<ACT, OUT>(smem, A, Bm, bias, Cb,
                           blockIdx.x * 256, blockIdx.y * 256, N, K);
}

// ---------------------------------------------------------------------------
// Flash attention over PACKED keys (exact; masked keys skipped).
// 4 waves x 32 q-rows; K-tile = 64 keys, double-buffered; 48KB LDS -> 3/CU.
// grid (64 bh, 8 qb) -- natural order (r10's XCD grouping regressed).
// ---------------------------------------------------------------------------
__global__ __launch_bounds__(256)
void attn_k(const bf16_t* __restrict__ Q, const bf16_t* __restrict__ Kg,
            const bf16_t* __restrict__ Vt, const float* __restrict__ maskf,
            const int* __restrict__ cntpad, bf16_t* __restrict__ O)
{
    __shared__ __align__(16) bf16_t Ks[2][64*64];  // [key][d]  swizzled
    __shared__ __align__(16) bf16_t Vs[2][64*64];  // [d][key]  swizzled
    __shared__ __align__(16) bf16_t Ps[4][32*64];  // per-wave P, swizzled
    const int tid  = threadIdx.x;
    const int lane = tid & 63;
    const int wave = tid >> 6;
    const int quad = lane >> 4, l16 = lane & 15;
    const int sw = l16 & 7;
    const int bh = blockIdx.x;
    const int b = bh >> 3, h = bh & 7;
    const int q0 = blockIdx.y * 128;
    const int kend = cntpad[b];

    bf8v qf[2][2];
#pragma unroll
    for (int qi = 0; qi < 2; ++qi) {
        const bf16_t* Qp = Q + (size_t)(b*NS + q0 + wave*32 + qi*16 + l16) * NE + h*ND;
        qf[qi][0] = *(const bf8v*)(Qp + quad*8);
        qf[qi][1] = *(const bf8v*)(Qp + 32 + quad*8);
    }

    f4 oacc[2][4] = {};
    float rs[2] = {0.f, 0.f};

    const int srow = tid >> 3;
    const int scol = (((tid & 7) ^ (srow & 7)) << 3);
    const float c1 = 0.125f * LOG2E;

    auto stage = [&](int buf, int kt) {
#pragma unroll
        for (int r = 0; r < 2; ++r) {
            async_copy16(Kg + (size_t)(b*NS + kt + r*32 + srow) * NE + h*ND + scol,
                         Ks[buf] + (r*256 + tid) * 8);
            async_copy16(Vt + (size_t)(bh*ND + r*32 + srow) * NS + kt + scol,
                         Vs[buf] + (r*256 + tid) * 8);
        }
    };

    stage(0, 0);
    int buf = 0;
    for (int kt = 0; kt < kend; kt += 64, buf ^= 1) {
        __syncthreads();
        if (kt + 64 < kend) stage(buf ^ 1, kt + 64);

        // S = Q*K^T (swapped): sacc[qi][j][r] = S[q=...+l16][key=j*16+quad*4+r]
        f4 sacc[2][4] = {};
        __builtin_amdgcn_s_setprio(1);
#pragma unroll
        for (int j = 0; j < 4; ++j) {
            bf8v kf0 = *(const bf8v*)(Ks[buf] + (j*16 + l16)*64 + ((quad    ) ^ sw)*8);
            bf8v kf1 = *(const bf8v*)(Ks[buf] + (j*16 + l16)*64 + ((quad + 4) ^ sw)*8);
#pragma unroll
            for (int qi = 0; qi < 2; ++qi) {
                sacc[qi][j] = __builtin_amdgcn_mfma_f32_16x16x32_bf16(kf0, qf[qi][0], sacc[qi][j], 0, 0, 0);
                sacc[qi][j] = __builtin_amdgcn_mfma_f32_16x16x32_bf16(kf1, qf[qi][1], sacc[qi][j], 0, 0, 0);
            }
        }
        __builtin_amdgcn_s_setprio(0);

        // P = exp2(S*c1 + mask); packed 8B writes to per-wave LDS (A-layout)
        bf16_t* Pw = Ps[wave];
#pragma unroll
        for (int j = 0; j < 4; ++j) {
            const f4 mkv = *(const f4*)(maskf + b*NS + kt + j*16 + quad*4);
#pragma unroll
            for (int qi = 0; qi < 2; ++qi) {
                bf4v o;
#pragma unroll
                for (int r = 0; r < 4; ++r) {
                    const float p = EXP2F(fmaf(sacc[qi][j][r], c1, mkv[r]));
                    rs[qi] += p;
                    o[r] = (bf16_t)p;
                }
                const int row = qi*16 + l16;
                const int chunk = (j*2 + (quad >> 1)) ^ sw;
                *(bf4v*)(Pw + row*64 + chunk*8 + (quad & 1)*4) = o;
            }
        }

        // O += P*V (swapped): oacc[qi][nt][r] = O[q=l16][d=nt*16+quad*4+r]
        __builtin_amdgcn_s_setprio(1);
#pragma unroll
        for (int ks = 0; ks < 2; ++ks) {
            bf8v pf[2];
#pragma unroll
            for (int qi = 0; qi < 2; ++qi)
                pf[qi] = *(const bf8v*)(Pw + (qi*16 + l16)*64 + ((ks*4 + quad) ^ sw)*8);
#pragma unroll
            for (int nt = 0; nt < 4; ++nt) {
                bf8v vf = *(const bf8v*)(Vs[buf] + (nt*16 + l16)*64 + ((ks*4 + quad) ^ sw)*8);
#pragma unroll
                for (int qi = 0; qi < 2; ++qi)
                    oacc[qi][nt] = __builtin_amdgcn_mfma_f32_16x16x32_bf16(vf, pf[qi], oacc[qi][nt], 0, 0, 0);
            }
        }
        __builtin_amdgcn_s_setprio(0);
    }

    // reduce row sums across quads (scalar per lane), scale, packed stores
#pragma unroll
    for (int qi = 0; qi < 2; ++qi) {
        float s = rs[qi];
        s += __shfl_xor(s, 16, 64);
        s += __shfl_xor(s, 32, 64);
        const float inv = 1.0f / s;
        const size_t row = (size_t)(b*NS + q0 + wave*32 + qi*16 + l16);
#pragma unroll
        for (int nt = 0; nt < 4; ++nt) {
            bf4v o;
#pragma unroll
            for (int r = 0; r < 4; ++r) o[r] = (bf16_t)(oacc[qi][nt][r] * inv);
            *(bf4v*)(O + row * NE + h*ND + nt*16 + quad*4) = o;
        }
    }
}

// ---------------------------------------------------------------------------
// In-place LayerNorm over the bf16 residual stream (after FFN2).
// Vectorized wave-per-row: 4 rows/block, bf8v 16B loads/stores (r9 config).
// ---------------------------------------------------------------------------
__global__ __launch_bounds__(256)
void ln_k(bf16_t* __restrict__ xb,
          const float* __restrict__ gamma, const float* __restrict__ beta,
          float* __restrict__ fout, int wf)
{
    const int wave = threadIdx.x >> 6, lane = threadIdx.x & 63;
    const size_t row  = (size_t)blockIdx.x * 4 + wave;
    const size_t base = row * NE;
    const f4 g0 = *(const f4*)(gamma + lane*8);
    const f4 g1 = *(const f4*)(gamma + lane*8 + 4);
    const f4 b0 = *(const f4*)(beta  + lane*8);
    const f4 b1 = *(const f4*)(beta  + lane*8 + 4);
    const bf8v v = *(const bf8v*)(xb + base + lane*8);
    float xv[8], s = 0.f, ss = 0.f;
#pragma unroll
    for (int r = 0; r < 8; ++r) { xv[r] = (float)v[r]; s += xv[r]; ss += xv[r]*xv[r]; }
#pragma unroll
    for (int off = 32; off > 0; off >>= 1) {
        s  += __shfl_xor(s,  off, 64);
        ss += __shfl_xor(ss, off, 64);
    }
    const float mean = s * (1.0f / NE);
    const float var  = ss * (1.0f / NE) - mean * mean;
    const float inv  = rsqrtf(var + 1e-5f);
    f4 o0, o1;
    bf8v ob;
#pragma unroll
    for (int r = 0; r < 4; ++r) {
        o0[r] = g0[r] * ((xv[r]     - mean) * inv) + b0[r];
        o1[r] = g1[r] * ((xv[r + 4] - mean) * inv) + b1[r];
        ob[r]     = (bf16_t)o0[r];
        ob[r + 4] = (bf16_t)o1[r];
    }
    *(bf8v*)(xb + base + lane*8) = ob;
    if (wf) {
        *(f4*)(fout + base + lane*8)     = o0;
        *(f4*)(fout + base + lane*8 + 4) = o1;
    }
}

// ---------------------------------------------------------------------------
// One-shot fp32->bf16 conversion of all 6 weight tensors + x, WITH mask
// packing fused in (8 extra blocks; pack runs in wave 0) -- one fewer
// dispatch (kept from r10: one-time cost, no per-layer effect).
// ---------------------------------------------------------------------------
#define W4SZ ((size_t)NL*NE*NE/4)     // float4s per E x E weight set
#define WBSZ ((size_t)NL*NE*NHF/4)    // float4s per E x HF weight set
#define XSZ  ((size_t)NROW*NE/4)      // float4s for x
#define CVT_TOTAL (4*W4SZ + 2*WBSZ + XSZ)
#define CVT_BLOCKS ((unsigned)((CVT_TOTAL + 255) / 256))

__global__ void cvt_pack_k(const float* __restrict__ wq, const float* __restrict__ wk,
                           const float* __restrict__ wv, const float* __restrict__ wo,
                           const float* __restrict__ w1, const float* __restrict__ w2,
                           const float* __restrict__ x,
                           bf16_t* __restrict__ owq, bf16_t* __restrict__ owk,
                           bf16_t* __restrict__ owv, bf16_t* __restrict__ owo,
                           bf16_t* __restrict__ ow1, bf16_t* __restrict__ ow2,
                           bf16_t* __restrict__ ox,
                           const int* __restrict__ m, unsigned short* __restrict__ rank,
                           int* __restrict__ cntpad, float* __restrict__ maskp)
{
    if (blockIdx.x >= CVT_BLOCKS) {
        // ---- mask packing: one block per batch, wave 0 only ----
        if (threadIdx.x >= 64) return;
        const int b = blockIdx.x - CVT_BLOCKS, lane = threadIdx.x;
        unsigned long long bals[16];
        int cnt = 0;
#pragma unroll
        for (int c = 0; c < 16; ++c) {
            const bool mk = m[b*NS + c*64 + lane] != 0;
            bals[c] = __ballot(mk);
            cnt += __popcll(bals[c]);
        }
        int u = 0, kk = 0;
#pragma unroll
        for (int c = 0; c < 16; ++c) {
            const unsigned long long bal = bals[c];
            const bool mk = (bal >> lane) & 1;
            const int pu = __popcll(bal & ((1ull << lane) - 1));
            const int r = mk ? (u + pu) : (cnt + kk + (lane - pu));
            rank[b*NS + c*64 + lane] = (unsigned short)r;
            const int cb = __popcll(bal);
            u += cb; kk += 64 - cb;
        }
        if (lane == 0) {
            int cp = (cnt + 63) & ~63;
            cntpad[b] = cp < 64 ? 64 : cp;
        }
#pragma unroll
        for (int c = 0; c < 16; ++c) {
            const int j = c*64 + lane;
            maskp[b*NS + j] = (j < cnt) ? 0.0f : -1.0e6f * LOG2E;
        }
        return;
    }
    size_t i = (size_t)blockIdx.x * 256 + threadIdx.x;
    if (i >= CVT_TOTAL) return;
    const float* src; bf16_t* dst;
    if      (i < 1*W4SZ)           { src = wq; dst = owq; }
    else if (i < 2*W4SZ)           { src = wk; dst = owk; i -= 1*W4SZ; }
    else if (i < 3*W4SZ)           { src = wv; dst = owv; i -= 2*W4SZ; }
    else if (i < 4*W4SZ)           { src = wo; dst = owo; i -= 3*W4SZ; }
    else if (i < 4*W4SZ + WBSZ)    { src = w1; dst = ow1; i -= 4*W4SZ; }
    else if (i < 4*W4SZ + 2*WBSZ)  { src = w2; dst = ow2; i -= 4*W4SZ + WBSZ; }
    else                           { src = x;  dst = ox;  i -= 4*W4SZ + 2*WBSZ; }
    const f4 v = ((const f4*)src)[i];
    bf4v o;
    o[0] = (bf16_t)v[0]; o[1] = (bf16_t)v[1]; o[2] = (bf16_t)v[2]; o[3] = (bf16_t)v[3];
    ((bf4v*)dst)[i] = o;
}

// ---------------------------------------------------------------------------
extern "C" void kernel_launch(void* const* d_in, const int* in_sizes, int n_in,
                              void* d_out, int out_size, void* d_ws, size_t ws_size,
                              hipStream_t stream)
{
    (void)in_sizes; (void)n_in; (void)out_size; (void)ws_size;
    const float* x   = (const float*)d_in[0];
    const int*   msk = (const int*)d_in[1];
    const float* WQ = (const float*)d_in[2];  const float* bQ  = (const float*)d_in[3];
    const float* WK = (const float*)d_in[4];  const float* bK  = (const float*)d_in[5];
    const float* WV = (const float*)d_in[6];  const float* bV  = (const float*)d_in[7];
    const float* WO = (const float*)d_in[8];  const float* bO  = (const float*)d_in[9];
    const float* W1 = (const float*)d_in[10]; const float* b1  = (const float*)d_in[11];
    const float* W2 = (const float*)d_in[12]; const float* b2  = (const float*)d_in[13];
    const float* g1 = (const float*)d_in[14]; const float* bt1 = (const float*)d_in[15];
    const float* g2 = (const float*)d_in[16]; const float* bt2 = (const float*)d_in[17];

    char* ws = (char*)d_ws;
    size_t off = 0;
    auto alloc = [&](size_t bytes) { char* p = ws + off; off += (bytes + 255) & ~(size_t)255; return p; };
    bf16_t* xb    = (bf16_t*)alloc((size_t)NROW*NE*2);
    bf16_t* Qb    = (bf16_t*)alloc((size_t)NROW*NE*2);
    bf16_t* Kb    = (bf16_t*)alloc((size_t)NROW*NE*2);
    bf16_t* Vtb   = (bf16_t*)alloc((size_t)NROW*NE*2);
    bf16_t* AOb   = (bf16_t*)alloc((size_t)NROW*NE*2);
    bf16_t* hb    = (bf16_t*)alloc((size_t)NROW*NHF*2);
    bf16_t* wqc   = (bf16_t*)alloc((size_t)NL*NE*NE*2);
    bf16_t* wkc   = (bf16_t*)alloc((size_t)NL*NE*NE*2);
    bf16_t* wvc   = (bf16_t*)alloc((size_t)NL*NE*NE*2);
    bf16_t* woc   = (bf16_t*)alloc((size_t)NL*NE*NE*2);
    bf16_t* w1c   = (bf16_t*)alloc((size_t)NL*NHF*NE*2);
    bf16_t* w2c   = (bf16_t*)alloc((size_t)NL*NE*NHF*2);
    float*  maskp = (float*) alloc((size_t)NB*NS*4);
    unsigned short* rankb = (unsigned short*)alloc((size_t)NB*NS*2);
    int*    cntp  = (int*)   alloc(NB*4);

    cvt_pack_k<<<dim3(CVT_BLOCKS + NB), dim3(256), 0, stream>>>(
        WQ, WK, WV, WO, W1, W2, x, wqc, wkc, wvc, woc, w1c, w2c, xb,
        msk, rankb, cntp, maskp);

    for (int l = 0; l < NL; ++l) {
        const bf16_t* wq  = wqc + (size_t)l*NE*NE;
        const bf16_t* wk  = wkc + (size_t)l*NE*NE;
        const bf16_t* wv  = wvc + (size_t)l*NE*NE;
        const bf16_t* wo  = woc + (size_t)l*NE*NE;
        const bf16_t* w1p = w1c + (size_t)l*NHF*NE;
        const bf16_t* w2p = w2c + (size_t)l*NE*NHF;
        const int last = (l == NL - 1);

        gemm_qkv_k<<<dim3(64, 8), dim3(256), 0, stream>>>(
            xb, wq, wk, wv, bQ + l*NE, bK + l*NE, bV + l*NE, Qb, Kb, Vtb, rankb);
        attn_k<<<dim3(64, 8), dim3(256), 0, stream>>>(Qb, Kb, Vtb, maskp, cntp, AOb);
        gemm_rmw_ln_k<<<dim3(256), dim3(512), 0, stream>>>(
            AOb, wo, bO + l*NE, xb, g1 + l*NE, bt1 + l*NE,
            nullptr, 0, NE);                              // xb = LN1(xb + O-proj)
        gemm256_k<1, 1><<<dim3(32, 8), dim3(512), 0, stream>>>(
            xb, w1p, b1 + l*NHF, hb, NHF, NE);
        gemm_bt_k<128, 0, 2><<<dim3(64, 4), dim3(256), 0, stream>>>(
            hb, w2p, b2 + l*NE, xb, NE, NHF);             // xb += FFN2
        ln_k<<<dim3(NROW/4), dim3(256), 0, stream>>>(
            xb, g2 + l*NE, bt2 + l*NE, (float*)d_out, last);
    }
}

// Round 12
// 867.297 us; speedup vs baseline: 1.0998x; 1.0166x over previous
//
#include <hip/hip_runtime.h>
#include <cstdint>
#include <cstddef>

#define NB 8
#define NS 1024
#define NE 512
#define NH 8
#define ND 64
#define NL 6
#define NHF 2048
#define NROW (NB*NS)   // 8192

typedef __bf16 bf16_t;
typedef __bf16 bf8v __attribute__((ext_vector_type(8)));
typedef __bf16 bf4v __attribute__((ext_vector_type(4)));
typedef float  f4   __attribute__((ext_vector_type(4)));

extern "C" __device__ float __ocml_native_exp2_f32(float);
#define EXP2F __ocml_native_exp2_f32
#define LOG2E 1.4426950408889634f

// ---- async global->LDS, 16B per lane (LDS dest = wave-uniform base + lane*16) ----
__device__ __forceinline__ void async_copy16(const bf16_t* g, bf16_t* l) {
    __builtin_amdgcn_global_load_lds(
        (const __attribute__((address_space(1))) void*)g,
        (__attribute__((address_space(3))) void*)l,
        16, 0, 0);
}

// gelu(x) = x * sigmoid(2*0.7978845608*(x+0.044715x^3)); exp2-domain, v_rcp.
__device__ __forceinline__ float gelu_f(float x) {
    const float s = fmaf(0.044715f * x * x, x, x);
    const float e = EXP2F(-2.3022081995f * s);   // 2*0.7978845608*log2(e)
    return x * __builtin_amdgcn_rcpf(1.0f + e);
}

// ---------------------------------------------------------------------------
// Core bf16 GEMM (128xBN, m97-structure): C[M,N] = A[M,K]*B[N,K]^T.
// OUT: 1 = bf16 row-major (swapped mfma -> 8B stores)
//      2 = bf16 in-place residual RMW (swapped)
// FFN2 uses BN=64 grid (64,8) = 512 blocks = 2 blocks/CU (8 waves/CU):
// BN=128's grid (64,4) left 1 block/CU = 1 wave/SIMD -- every per-K-iter
// vmcnt(0) drain fully exposed (m114: overlap needs co-resident waves).
// NOTE (r8): cross-block LN fusion w/ device fences = 4x loss. Stay split.
// NOTE (r10): XCD-swizzled block remaps on these L3-resident tiles cost
// ~75us total -- natural 2-D grid order is faster here. Do not re-land.
// ---------------------------------------------------------------------------
template<int BN, int ACT, int OUT>
__device__ __forceinline__ void gemm_core(
    bf16_t* __restrict__ sm,
    const bf16_t* __restrict__ A, const bf16_t* __restrict__ Bm,
    const float* __restrict__ bias, bf16_t* __restrict__ Cb,
    int m0, int n0, int N, int K)
{
    constexpr int JN = BN / 32, WSPAN = BN / 2;
    bf16_t* As = sm;             // 2 x 8192
    bf16_t* Bs = sm + 2*128*64;  // 2 x (BN*64)
    const int tid  = threadIdx.x;
    const int lane = tid & 63;
    const int wave = tid >> 6;
    const int wm = wave >> 1, wn = wave & 1;
    const int quad = lane >> 4, l16 = lane & 15;
    const int srow = tid >> 3;                         // 0..31
    const int scol = (((tid & 7) ^ (srow & 7)) << 3);  // swizzled source col

    f4 acc[4][JN] = {};

    const bf16_t* Ag = A  + (size_t)(m0 + srow) * K + scol;
    const bf16_t* Bg = Bm + (size_t)(n0 + srow) * K + scol;
    const int sw = (l16 & 7);

    auto stage = [&](int buf, int kt) {
#pragma unroll
        for (int r = 0; r < 4; ++r)
            async_copy16(Ag + (size_t)r * 32 * K + kt, As + buf*8192 + tid*8 + r*2048);
#pragma unroll
        for (int r = 0; r < BN/32; ++r)
            async_copy16(Bg + (size_t)r * 32 * K + kt, Bs + buf*(BN*64) + tid*8 + r*2048);
    };

    stage(0, 0);
    int buf = 0;
    for (int kt = 0; kt < K; kt += 64, buf ^= 1) {
        __syncthreads();                       // drains buf's loads; frees buf^1
        if (kt + 64 < K) stage(buf ^ 1, kt + 64);
        const bf16_t* Ab = As + buf*8192;
        const bf16_t* Bb = Bs + buf*(BN*64);
#pragma unroll
        for (int s = 0; s < 2; ++s) {
            const int c8 = ((s*4 + quad) ^ sw) * 8;
            bf8v af[4], bfv[JN];
#pragma unroll
            for (int i = 0; i < 4; ++i)
                af[i] = *(const bf8v*)(Ab + (wm*64 + i*16 + l16)*64 + c8);
#pragma unroll
            for (int j = 0; j < JN; ++j)
                bfv[j] = *(const bf8v*)(Bb + (wn*WSPAN + j*16 + l16)*64 + c8);
#pragma unroll
            for (int i = 0; i < 4; ++i)
#pragma unroll
                for (int j = 0; j < JN; ++j)
                    acc[i][j] = __builtin_amdgcn_mfma_f32_16x16x32_bf16(bfv[j], af[i], acc[i][j], 0, 0, 0);
        }
    }

    // swapped layout: m = ...+l16, n = ...+quad*4+r (4 consecutive n/lane)
#pragma unroll
    for (int i = 0; i < 4; ++i) {
        const int mi = m0 + wm*64 + i*16 + l16;
        const size_t m = (size_t)mi;
#pragma unroll
        for (int j = 0; j < JN; ++j) {
            const int nb = n0 + wn*WSPAN + j*16 + quad*4;
            const f4 bv = *(const f4*)(bias + nb);
            f4 v = acc[i][j] + bv;
            if (ACT) {
#pragma unroll
                for (int r = 0; r < 4; ++r) v[r] = gelu_f(v[r]);
            }
            bf4v* cp = (bf4v*)(Cb + m * (size_t)N + nb);
            bf4v o;
            if (OUT == 2) {
                const bf4v old = *cp;
#pragma unroll
                for (int r = 0; r < 4; ++r) o[r] = (bf16_t)((float)old[r] + v[r]);
            } else {
#pragma unroll
                for (int r = 0; r < 4; ++r) o[r] = (bf16_t)v[r];
            }
            *cp = o;
        }
    }
}

template<int BN, int ACT, int OUT>
__global__ __launch_bounds__(256)
void gemm_bt_k(const bf16_t* __restrict__ A, const bf16_t* __restrict__ Bm,
               const float* __restrict__ bias, bf16_t* __restrict__ Cb, int N, int K)
{
    __shared__ __align__(16) bf16_t smem[2*128*64 + 2*BN*64];
    gemm_core<BN, ACT, OUT>(smem, A, Bm, bias, Cb,
                            blockIdx.x * 128, blockIdx.y * BN, N, K);
}

// ---------------------------------------------------------------------------
// Fused residual-RMW + LayerNorm GEMM:  xb = LN(xb + A*B^T + bias) (per row).
// O-PROJ ONLY (K=512): intra-block fusion (block owns whole rows).
// Tile: 32 rows x 512 cols; 512 thr; grid 256 = 1/CU (8 waves/CU).
// ---------------------------------------------------------------------------
__global__ __launch_bounds__(512, 2)
void gemm_rmw_ln_k(const bf16_t* __restrict__ A, const bf16_t* __restrict__ Bm,
                   const float* __restrict__ bias, bf16_t* __restrict__ xb,
                   const float* __restrict__ gamma, const float* __restrict__ beta,
                   float* __restrict__ fout, int wf, int K)
{
    __shared__ __align__(16) bf16_t As[2*32*64];     // 8 KB
    __shared__ __align__(16) bf16_t Bs[2*512*64];    // 128 KB
    __shared__ float wsum[8][32], wssq[8][32];
    const int tid  = threadIdx.x;          // 0..511
    const int lane = tid & 63;
    const int wave = tid >> 6;             // 0..7 ; wave owns cols wave*64..+63
    const int quad = lane >> 4, l16 = lane & 15;
    const int sw = l16 & 7;
    const int srow = tid >> 3;             // 0..63
    const int scol = ((tid & 7) ^ (srow & 7)) << 3;
    const int m0 = blockIdx.x * 32;

    const bf16_t* Ag = A  + (size_t)(m0 + srow) * K + scol;   // rows 0..31 (tid<256)
    const bf16_t* Bg = Bm + (size_t)srow * K + scol;          // + r*64 rows

    f4 acc[2][4] = {};

    auto stage = [&](int buf, int kt) {
        if (tid < 256)                                   // wave-uniform (4 waves)
            async_copy16(Ag + kt, As + buf*2048 + tid*8);
#pragma unroll
        for (int r = 0; r < 8; ++r)
            async_copy16(Bg + (size_t)r * 64 * K + kt, Bs + buf*32768 + (r*512 + tid)*8);
    };

    stage(0, 0);
    int buf = 0;
    for (int kt = 0; kt < K; kt += 64, buf ^= 1) {
        __syncthreads();                   // drains buf's loads; frees buf^1
        if (kt + 64 < K) stage(buf ^ 1, kt + 64);
        const bf16_t* Ab = As + buf*2048;
        const bf16_t* Bb = Bs + buf*32768;
#pragma unroll
        for (int s = 0; s < 2; ++s) {
            const int c8 = ((s*4 + quad) ^ sw) * 8;
            bf8v af[2], bfv[4];
#pragma unroll
            for (int i = 0; i < 2; ++i)
                af[i] = *(const bf8v*)(Ab + (i*16 + l16)*64 + c8);
#pragma unroll
            for (int j = 0; j < 4; ++j)
                bfv[j] = *(const bf8v*)(Bb + (wave*64 + j*16 + l16)*64 + c8);
#pragma unroll
            for (int i = 0; i < 2; ++i)
#pragma unroll
                for (int j = 0; j < 4; ++j)
                    acc[i][j] = __builtin_amdgcn_mfma_f32_16x16x32_bf16(bfv[j], af[i], acc[i][j], 0, 0, 0);
        }
    }

    // ---- epilogue: residual RMW, row stats, LN, store ----
    // swapped layout: row = i*16+l16, col = wave*64 + j*16 + quad*4 + r
    f4 v[2][4];
    float ps[2], pss[2];
#pragma unroll
    for (int i = 0; i < 2; ++i) {
        ps[i] = 0.f; pss[i] = 0.f;
        const size_t m = (size_t)(m0 + i*16 + l16);
#pragma unroll
        for (int j = 0; j < 4; ++j) {
            const int nb = wave*64 + j*16 + quad*4;
            const f4 bv = *(const f4*)(bias + nb);
            const bf4v old = *(const bf4v*)(xb + m * NE + nb);
            f4 t = acc[i][j] + bv;
#pragma unroll
            for (int r = 0; r < 4; ++r) {
                t[r] += (float)old[r];
                ps[i]  += t[r];
                pss[i] += t[r] * t[r];
            }
            v[i][j] = t;
        }
        // reduce across the 4 quads (lanes sharing l16)
        ps[i]  += __shfl_xor(ps[i], 16, 64);
        ps[i]  += __shfl_xor(ps[i], 32, 64);
        pss[i] += __shfl_xor(pss[i], 16, 64);
        pss[i] += __shfl_xor(pss[i], 32, 64);
    }
    if (quad == 0) {
#pragma unroll
        for (int i = 0; i < 2; ++i) {
            wsum[wave][i*16 + l16] = ps[i];
            wssq[wave][i*16 + l16] = pss[i];
        }
    }
    __syncthreads();
#pragma unroll
    for (int i = 0; i < 2; ++i) {
        const int row = i*16 + l16;
        float s = 0.f, ss = 0.f;
#pragma unroll
        for (int w = 0; w < 8; ++w) { s += wsum[w][row]; ss += wssq[w][row]; }
        const float mean = s * (1.0f / NE);
        const float var  = ss * (1.0f / NE) - mean * mean;
        const float inv  = rsqrtf(var + 1e-5f);
        const size_t m = (size_t)(m0 + row);
#pragma unroll
        for (int j = 0; j < 4; ++j) {
            const int nb = wave*64 + j*16 + quad*4;
            const f4 gm = *(const f4*)(gamma + nb);
            const f4 bt = *(const f4*)(beta + nb);
            f4 o;
            bf4v ob;
#pragma unroll
            for (int r = 0; r < 4; ++r) {
                o[r]  = gm[r] * ((v[i][j][r] - mean) * inv) + bt[r];
                ob[r] = (bf16_t)o[r];
            }
            *(bf4v*)(xb + m * NE + nb) = ob;
            if (wf) *(f4*)(fout + m * NE + nb) = o;
        }
    }
}

// ---------------------------------------------------------------------------
// Truly fused QKV: ONE block computes Q, K and V for a 128m x 64n tile,
// staging the shared A (x) tile ONCE per K-iter plus three 64-row B tiles.
// grid (64,8) = 512 blocks = 2/CU (LDS 80 KB).
// ---------------------------------------------------------------------------
__global__ __launch_bounds__(256, 2)
void gemm_qkv_k(const bf16_t* __restrict__ A,
                const bf16_t* __restrict__ wq, const bf16_t* __restrict__ wk, const bf16_t* __restrict__ wv,
                const float* __restrict__ bq, const float* __restrict__ bk, const float* __restrict__ bv,
                bf16_t* __restrict__ Q, bf16_t* __restrict__ K, bf16_t* __restrict__ Vt,
                const unsigned short* __restrict__ rank)
{
    __shared__ __align__(16) bf16_t As_[2*128*64];      // 32 KB, dbuf
    __shared__ __align__(16) bf16_t Bs_[3][2*64*64];    // 48 KB, dbuf x {Q,K,V}
    const int tid  = threadIdx.x;
    const int lane = tid & 63;
    const int wave = tid >> 6;
    const int wm = wave >> 1, wn = wave & 1;
    const int quad = lane >> 4, l16 = lane & 15;
    const int sw = l16 & 7;
    const int srow = tid >> 3;                         // 0..31
    const int scol = (((tid & 7) ^ (srow & 7)) << 3);  // swizzled source col
    const int m0 = blockIdx.x * 128, n0 = blockIdx.y * 64;

    const bf16_t* Ag = A + (size_t)(m0 + srow) * NE + scol;
    const bf16_t* Wg0 = wq + (size_t)(n0 + srow) * NE + scol;
    const bf16_t* Wg1 = wk + (size_t)(n0 + srow) * NE + scol;
    const bf16_t* Wg2 = wv + (size_t)(n0 + srow) * NE + scol;

    f4 acc[3][4][2] = {};

    auto stage = [&](int buf, int kt) {
#pragma unroll
        for (int r = 0; r < 4; ++r)
            async_copy16(Ag + (size_t)r*32*NE + kt, As_ + buf*8192 + tid*8 + r*2048);
#pragma unroll
        for (int r = 0; r < 2; ++r) {
            async_copy16(Wg0 + (size_t)r*32*NE + kt, Bs_[0] + buf*4096 + tid*8 + r*2048);
            async_copy16(Wg1 + (size_t)r*32*NE + kt, Bs_[1] + buf*4096 + tid*8 + r*2048);
            async_copy16(Wg2 + (size_t)r*32*NE + kt, Bs_[2] + buf*4096 + tid*8 + r*2048);
        }
    };

    stage(0, 0);
    int buf = 0;
    for (int kt = 0; kt < NE; kt += 64, buf ^= 1) {
        __syncthreads();
        if (kt + 64 < NE) stage(buf ^ 1, kt + 64);
        const bf16_t* Ab = As_ + buf*8192;
#pragma unroll
        for (int s = 0; s < 2; ++s) {
            const int c8 = ((s*4 + quad) ^ sw) * 8;
            bf8v af[4];
#pragma unroll
            for (int i = 0; i < 4; ++i)
                af[i] = *(const bf8v*)(Ab + (wm*64 + i*16 + l16)*64 + c8);
#pragma unroll
            for (int mat = 0; mat < 3; ++mat) {
                const bf16_t* Bb = Bs_[mat] + buf*4096;
                const bf8v b0 = *(const bf8v*)(Bb + (wn*32      + l16)*64 + c8);
                const bf8v b1 = *(const bf8v*)(Bb + (wn*32 + 16 + l16)*64 + c8);
                if (mat < 2) {
#pragma unroll
                    for (int i = 0; i < 4; ++i) {
                        acc[mat][i][0] = __builtin_amdgcn_mfma_f32_16x16x32_bf16(b0, af[i], acc[mat][i][0], 0, 0, 0);
                        acc[mat][i][1] = __builtin_amdgcn_mfma_f32_16x16x32_bf16(b1, af[i], acc[mat][i][1], 0, 0, 0);
                    }
                } else {   // V: natural order for the scatter epilogue layout
#pragma unroll
                    for (int i = 0; i < 4; ++i) {
                        acc[2][i][0] = __builtin_amdgcn_mfma_f32_16x16x32_bf16(af[i], b0, acc[2][i][0], 0, 0, 0);
                        acc[2][i][1] = __builtin_amdgcn_mfma_f32_16x16x32_bf16(af[i], b1, acc[2][i][1], 0, 0, 0);
                    }
                }
            }
        }
    }

    // Q (row-major) + K (rank-packed rows): swapped layout, 8B stores.
#pragma unroll
    for (int i = 0; i < 4; ++i) {
        const int mi = m0 + wm*64 + i*16 + l16;
        const int mk = (mi & ~1023) + (int)rank[mi];
#pragma unroll
        for (int j = 0; j < 2; ++j) {
            const int nb = n0 + wn*32 + j*16 + quad*4;
            const f4 vq = acc[0][i][j] + *(const f4*)(bq + nb);
            const f4 vk = acc[1][i][j] + *(const f4*)(bk + nb);
            bf4v oq, ok;
#pragma unroll
            for (int r = 0; r < 4; ++r) { oq[r] = (bf16_t)vq[r]; ok[r] = (bf16_t)vk[r]; }
            *(bf4v*)(Q + (size_t)mi * NE + nb) = oq;
            *(bf4v*)(K + (size_t)mk * NE + nb) = ok;
        }
    }
    // V: natural layout (m = ...+quad*4+r, n = ...+l16), packed column scatter.
#pragma unroll
    for (int j = 0; j < 2; ++j) {
        const int n = n0 + wn*32 + j*16 + l16;
        const float bvv = bv[n];
#pragma unroll
        for (int i = 0; i < 4; ++i) {
            const int mbase = m0 + wm*64 + i*16 + quad*4;
            const size_t b8h = (size_t)((mbase >> 10)*8 + (n >> 6));
            bf16_t* rowp = Vt + (b8h*64 + (size_t)(n & 63))*1024;
#pragma unroll
            for (int r = 0; r < 4; ++r)
                rowp[rank[mbase + r]] = (bf16_t)(acc[2][i][j][r] + bvv);
        }
    }
}

// ---------------------------------------------------------------------------
// 256x256 8-phase GEMM (T2+T3+T4+T5) -- FFN1 only (grid 32x8 = 256 = 1/CU).
// ---------------------------------------------------------------------------
template<int ACT, int OUT>
__device__ __forceinline__ void gemm256_core(
    bf16_t* __restrict__ sm,
    const bf16_t* __restrict__ A, const bf16_t* __restrict__ Bm,
    const float* __restrict__ bias, bf16_t* __restrict__ Cb,
    int m0, int n0, int N, int K)
{
    const int tid  = threadIdx.x;          // 0..511
    const int lane = tid & 63;
    const int wave = tid >> 6;             // 0..7
    const int wm = wave >> 2, wn = wave & 3;
    const int quad = lane >> 4, l16 = lane & 15;
    const int sw = l16 & 7;
    const int srow = tid >> 3;             // 0..63
    const int scol = ((tid & 7) ^ (srow & 7)) << 3;

    bf16_t* As = sm;                 // [dbuf][half][128][64]
    bf16_t* Bs = sm + 4 * 8192;

    const bf16_t* Ag = A  + (size_t)(m0 + srow) * K + scol;
    const bf16_t* Bg = Bm + (size_t)(n0 + srow) * K + scol;

    auto stageA = [&](int d, int h, int kt) {
        bf16_t* dst = As + (d*2 + h) * 8192 + tid * 8;
        const bf16_t* src = Ag + (size_t)(h * 128) * K + kt;
        async_copy16(src, dst);
        async_copy16(src + (size_t)64 * K, dst + 4096);
    };
    auto stageB = [&](int d, int h, int kt) {
        bf16_t* dst = Bs + (d*2 + h) * 8192 + tid * 8;
        const bf16_t* src = Bg + (size_t)(h * 128) * K + kt;
        async_copy16(src, dst);
        async_copy16(src + (size_t)64 * K, dst + 4096);
    };

    const int nt = K >> 6;

    f4 acc[8][4] = {};
    bf8v bfr[4][2], al[4][2], ah[4][2];

    auto mfmaQ = [&](const bf8v (&af)[4][2], int fb, int gb) {
#pragma unroll
        for (int kh = 0; kh < 2; ++kh)
#pragma unroll
            for (int f = 0; f < 4; ++f)
#pragma unroll
                for (int g = 0; g < 2; ++g)
                    acc[fb+f][gb+g] = __builtin_amdgcn_mfma_f32_16x16x32_bf16(bfr[gb+g][kh], af[f][kh], acc[fb+f][gb+g], 0, 0, 0);
    };

    stageB(0, 0, 0);  stageB(0, 1, 0);  stageA(0, 0, 0);  stageA(0, 1, 0);
    stageB(1, 0, 64); stageB(1, 1, 64); stageA(1, 0, 64);
    asm volatile("s_waitcnt vmcnt(6)" ::: "memory");
    __builtin_amdgcn_s_barrier();

    for (int t = 0; t < nt; ++t) {
        const int d = t & 1;
        const int kt2 = (t + 2) << 6;
        const bf16_t* Ab = As + (d*2 + wm) * 8192;
        const bf16_t* Bb = Bs + (d*2 + (wn >> 1)) * 8192 + (wn & 1) * 4096;

        // P1: all-B + A-low; stage A1(t+1)
#pragma unroll
        for (int g = 0; g < 4; ++g)
#pragma unroll
            for (int kh = 0; kh < 2; ++kh)
                bfr[g][kh] = *(const bf8v*)(Bb + (g*16 + l16)*64 + (((kh*4 + quad) ^ sw) << 3));
#pragma unroll
        for (int f = 0; f < 4; ++f)
#pragma unroll
            for (int kh = 0; kh < 2; ++kh)
                al[f][kh] = *(const bf8v*)(Ab + (f*16 + l16)*64 + (((kh*4 + quad) ^ sw) << 3));
        if (t + 1 < nt) stageA(d ^ 1, 1, (t + 1) << 6);
        __builtin_amdgcn_s_barrier();
        __builtin_amdgcn_s_setprio(1);
        mfmaQ(al, 0, 0);
        __builtin_amdgcn_s_setprio(0);
        asm volatile("s_waitcnt lgkmcnt(0)" ::: "memory");
        __builtin_amdgcn_s_barrier();

        // P2: A-high; stage B0(t+2)
#pragma unroll
        for (int f = 0; f < 4; ++f)
#pragma unroll
            for (int kh = 0; kh < 2; ++kh)
                ah[f][kh] = *(const bf8v*)(Ab + ((f + 4)*16 + l16)*64 + (((kh*4 + quad) ^ sw) << 3));
        if (t + 2 < nt) stageB(d, 0, kt2);
        __builtin_amdgcn_s_barrier();
        __builtin_amdgcn_s_setprio(1);
        mfmaQ(ah, 4, 0);
        __builtin_amdgcn_s_setprio(0);
        asm volatile("s_waitcnt lgkmcnt(0)" ::: "memory");
        __builtin_amdgcn_s_barrier();

        // P3: stage B1(t+2)
        if (t + 2 < nt) stageB(d, 1, kt2);
        __builtin_amdgcn_s_barrier();
        __builtin_amdgcn_s_setprio(1);
        mfmaQ(al, 0, 2);
        __builtin_amdgcn_s_setprio(0);
        asm volatile("s_waitcnt lgkmcnt(0)" ::: "memory");
        __builtin_amdgcn_s_barrier();

        // P4: stage A0(t+2); counted vmcnt
        if (t + 2 < nt) stageA(d, 0, kt2);
        __builtin_amdgcn_s_barrier();
        __builtin_amdgcn_s_setprio(1);
        mfmaQ(ah, 4, 2);
        __builtin_amdgcn_s_setprio(0);
        asm volatile("s_waitcnt lgkmcnt(0)" ::: "memory");
        if (t + 1 < nt) {
            if (t + 2 < nt) asm volatile("s_waitcnt vmcnt(6)" ::: "memory");
            else            asm volatile("s_waitcnt vmcnt(0)" ::: "memory");
        }
        __builtin_amdgcn_s_barrier();
    }

    // swapped layout: m = ...+l16, n = ...+quad*4+r
#pragma unroll
    for (int f = 0; f < 8; ++f) {
        const int mi = m0 + wm*128 + f*16 + l16;
        const size_t m = (size_t)mi;
#pragma unroll
        for (int g = 0; g < 4; ++g) {
            const int nb = n0 + wn*64 + g*16 + quad*4;
            const f4 bv = *(const f4*)(bias + nb);
            f4 v = acc[f][g] + bv;
            if (ACT) {
#pragma unroll
                for (int r = 0; r < 4; ++r) v[r] = gelu_f(v[r]);
            }
            bf4v* cp = (bf4v*)(Cb + m * (size_t)N + nb);
            bf4v o;
            if (OUT == 2) {
                const bf4v old = *cp;
#pragma unroll
                for (int r = 0; r < 4; ++r) o[r] = (bf16_t)((float)old[r] + v[r]);
            } else {
#pragma unroll
                for (int r = 0; r < 4; ++r) o[r] = (bf16_t)v[r];
            }
            *cp = o;
        }
    }
}

template<int ACT, int OUT>
__global__ __launch_bounds__(512, 2)
void gemm256_k(const bf16_t* __restrict__ A, const bf16_t* __restrict__ Bm,
               const float* __restrict__ bias, bf16_t* __restrict__ Cb, int N, int K)
{
    __shared__ __align__(16) bf16_t smem[8 * 8192];   // 128 KiB
    gemm256_core<ACT, OUT>(smem, A, Bm, bias, Cb,
                           blockIdx.x * 256, blockIdx.y * 256, N, K);
}

// ---------------------------------------------------------------------------
// Flash attention over PACKED keys (exact; masked keys skipped).
// 4 waves x 32 q-rows; K-tile = 64 keys, double-buffered; 48KB LDS -> 3/CU.
// grid (64 bh, 8 qb) -- natural order.
// ---------------------------------------------------------------------------
__global__ __launch_bounds__(256)
void attn_k(const bf16_t* __restrict__ Q, const bf16_t* __restrict__ Kg,
            const bf16_t* __restrict__ Vt, const float* __restrict__ maskf,
            const int* __restrict__ cntpad, bf16_t* __restrict__ O)
{
    __shared__ __align__(16) bf16_t Ks[2][64*64];  // [key][d]  swizzled
    __shared__ __align__(16) bf16_t Vs[2][64*64];  // [d][key]  swizzled
    __shared__ __align__(16) bf16_t Ps[4][32*64];  // per-wave P, swizzled
    const int tid  = threadIdx.x;
    const int lane = tid & 63;
    const int wave = tid >> 6;
    const int quad = lane >> 4, l16 = lane & 15;
    const int sw = l16 & 7;
    const int bh = blockIdx.x;
    const int b = bh >> 3, h = bh & 7;
    const int q0 = blockIdx.y * 128;
    const int kend = cntpad[b];

    bf8v qf[2][2];
#pragma unroll
    for (int qi = 0; qi < 2; ++qi) {
        const bf16_t* Qp = Q + (size_t)(b*NS + q0 + wave*32 + qi*16 + l16) * NE + h*ND;
        qf[qi][0] = *(const bf8v*)(Qp + quad*8);
        qf[qi][1] = *(const bf8v*)(Qp + 32 + quad*8);
    }

    f4 oacc[2][4] = {};
    float rs[2] = {0.f, 0.f};

    const int srow = tid >> 3;
    const int scol = (((tid & 7) ^ (srow & 7)) << 3);
    const float c1 = 0.125f * LOG2E;

    auto stage = [&](int buf, int kt) {
#pragma unroll
        for (int r = 0; r < 2; ++r) {
            async_copy16(Kg + (size_t)(b*NS + kt + r*32 + srow) * NE + h*ND + scol,
                         Ks[buf] + (r*256 + tid) * 8);
            async_copy16(Vt + (size_t)(bh*ND + r*32 + srow) * NS + kt + scol,
                         Vs[buf] + (r*256 + tid) * 8);
        }
    };

    stage(0, 0);
    int buf = 0;
    for (int kt = 0; kt < kend; kt += 64, buf ^= 1) {
        __syncthreads();
        if (kt + 64 < kend) stage(buf ^ 1, kt + 64);

        // S = Q*K^T (swapped): sacc[qi][j][r] = S[q=...+l16][key=j*16+quad*4+r]
        f4 sacc[2][4] = {};
        __builtin_amdgcn_s_setprio(1);
#pragma unroll
        for (int j = 0; j < 4; ++j) {
            bf8v kf0 = *(const bf8v*)(Ks[buf] + (j*16 + l16)*64 + ((quad    ) ^ sw)*8);
            bf8v kf1 = *(const bf8v*)(Ks[buf] + (j*16 + l16)*64 + ((quad + 4) ^ sw)*8);
#pragma unroll
            for (int qi = 0; qi < 2; ++qi) {
                sacc[qi][j] = __builtin_amdgcn_mfma_f32_16x16x32_bf16(kf0, qf[qi][0], sacc[qi][j], 0, 0, 0);
                sacc[qi][j] = __builtin_amdgcn_mfma_f32_16x16x32_bf16(kf1, qf[qi][1], sacc[qi][j], 0, 0, 0);
            }
        }
        __builtin_amdgcn_s_setprio(0);

        // P = exp2(S*c1 + mask); packed 8B writes to per-wave LDS (A-layout)
        bf16_t* Pw = Ps[wave];
#pragma unroll
        for (int j = 0; j < 4; ++j) {
            const f4 mkv = *(const f4*)(maskf + b*NS + kt + j*16 + quad*4);
#pragma unroll
            for (int qi = 0; qi < 2; ++qi) {
                bf4v o;
#pragma unroll
                for (int r = 0; r < 4; ++r) {
                    const float p = EXP2F(fmaf(sacc[qi][j][r], c1, mkv[r]));
                    rs[qi] += p;
                    o[r] = (bf16_t)p;
                }
                const int row = qi*16 + l16;
                const int chunk = (j*2 + (quad >> 1)) ^ sw;
                *(bf4v*)(Pw + row*64 + chunk*8 + (quad & 1)*4) = o;
            }
        }

        // O += P*V (swapped): oacc[qi][nt][r] = O[q=l16][d=nt*16+quad*4+r]
        __builtin_amdgcn_s_setprio(1);
#pragma unroll
        for (int ks = 0; ks < 2; ++ks) {
            bf8v pf[2];
#pragma unroll
            for (int qi = 0; qi < 2; ++qi)
                pf[qi] = *(const bf8v*)(Pw + (qi*16 + l16)*64 + ((ks*4 + quad) ^ sw)*8);
#pragma unroll
            for (int nt = 0; nt < 4; ++nt) {
                bf8v vf = *(const bf8v*)(Vs[buf] + (nt*16 + l16)*64 + ((ks*4 + quad) ^ sw)*8);
#pragma unroll
                for (int qi = 0; qi < 2; ++qi)
                    oacc[qi][nt] = __builtin_amdgcn_mfma_f32_16x16x32_bf16(vf, pf[qi], oacc[qi][nt], 0, 0, 0);
            }
        }
        __builtin_amdgcn_s_setprio(0);
    }

    // reduce row sums across quads (scalar per lane), scale, packed stores
#pragma unroll
    for (int qi = 0; qi < 2; ++qi) {
        float s = rs[qi];
        s += __shfl_xor(s, 16, 64);
        s += __shfl_xor(s, 32, 64);
        const float inv = 1.0f / s;
        const size_t row = (size_t)(b*NS + q0 + wave*32 + qi*16 + l16);
#pragma unroll
        for (int nt = 0; nt < 4; ++nt) {
            bf4v o;
#pragma unroll
            for (int r = 0; r < 4; ++r) o[r] = (bf16_t)(oacc[qi][nt][r] * inv);
            *(bf4v*)(O + row * NE + h*ND + nt*16 + quad*4) = o;
        }
    }
}

// ---------------------------------------------------------------------------
// In-place LayerNorm over the bf16 residual stream (after FFN2).
// Vectorized wave-per-row: 4 rows/block, bf8v 16B loads/stores.
// ---------------------------------------------------------------------------
__global__ __launch_bounds__(256)
void ln_k(bf16_t* __restrict__ xb,
          const float* __restrict__ gamma, const float* __restrict__ beta,
          float* __restrict__ fout, int wf)
{
    const int wave = threadIdx.x >> 6, lane = threadIdx.x & 63;
    const size_t row  = (size_t)blockIdx.x * 4 + wave;
    const size_t base = row * NE;
    const f4 g0 = *(const f4*)(gamma + lane*8);
    const f4 g1 = *(const f4*)(gamma + lane*8 + 4);
    const f4 b0 = *(const f4*)(beta  + lane*8);
    const f4 b1 = *(const f4*)(beta  + lane*8 + 4);
    const bf8v v = *(const bf8v*)(xb + base + lane*8);
    float xv[8], s = 0.f, ss = 0.f;
#pragma unroll
    for (int r = 0; r < 8; ++r) { xv[r] = (float)v[r]; s += xv[r]; ss += xv[r]*xv[r]; }
#pragma unroll
    for (int off = 32; off > 0; off >>= 1) {
        s  += __shfl_xor(s,  off, 64);
        ss += __shfl_xor(ss, off, 64);
    }
    const float mean = s * (1.0f / NE);
    const float var  = ss * (1.0f / NE) - mean * mean;
    const float inv  = rsqrtf(var + 1e-5f);
    f4 o0, o1;
    bf8v ob;
#pragma unroll
    for (int r = 0; r < 4; ++r) {
        o0[r] = g0[r] * ((xv[r]     - mean) * inv) + b0[r];
        o1[r] = g1[r] * ((xv[r + 4] - mean) * inv) + b1[r];
        ob[r]     = (bf16_t)o0[r];
        ob[r + 4] = (bf16_t)o1[r];
    }
    *(bf8v*)(xb + base + lane*8) = ob;
    if (wf) {
        *(f4*)(fout + base + lane*8)     = o0;
        *(f4*)(fout + base + lane*8 + 4) = o1;
    }
}

// ---------------------------------------------------------------------------
// One-shot fp32->bf16 conversion of all 6 weight tensors + x, WITH mask
// packing fused in (8 extra blocks; pack runs in wave 0).
// ---------------------------------------------------------------------------
#define W4SZ ((size_t)NL*NE*NE/4)     // float4s per E x E weight set
#define WBSZ ((size_t)NL*NE*NHF/4)    // float4s per E x HF weight set
#define XSZ  ((size_t)NROW*NE/4)      // float4s for x
#define CVT_TOTAL (4*W4SZ + 2*WBSZ + XSZ)
#define CVT_BLOCKS ((unsigned)((CVT_TOTAL + 255) / 256))

__global__ void cvt_pack_k(const float* __restrict__ wq, const float* __restrict__ wk,
                           const float* __restrict__ wv, const float* __restrict__ wo,
                           const float* __restrict__ w1, const float* __restrict__ w2,
                           const float* __restrict__ x,
                           bf16_t* __restrict__ owq, bf16_t* __restrict__ owk,
                           bf16_t* __restrict__ owv, bf16_t* __restrict__ owo,
                           bf16_t* __restrict__ ow1, bf16_t* __restrict__ ow2,
                           bf16_t* __restrict__ ox,
                           const int* __restrict__ m, unsigned short* __restrict__ rank,
                           int* __restrict__ cntpad, float* __restrict__ maskp)
{
    if (blockIdx.x >= CVT_BLOCKS) {
        // ---- mask packing: one block per batch, wave 0 only ----
        if (threadIdx.x >= 64) return;
        const int b = blockIdx.x - CVT_BLOCKS, lane = threadIdx.x;
        unsigned long long bals[16];
        int cnt = 0;
#pragma unroll
        for (int c = 0; c < 16; ++c) {
            const bool mk = m[b*NS + c*64 + lane] != 0;
            bals[c] = __ballot(mk);
            cnt += __popcll(bals[c]);
        }
        int u = 0, kk = 0;
#pragma unroll
        for (int c = 0; c < 16; ++c) {
            const unsigned long long bal = bals[c];
            const bool mk = (bal >> lane) & 1;
            const int pu = __popcll(bal & ((1ull << lane) - 1));
            const int r = mk ? (u + pu) : (cnt + kk + (lane - pu));
            rank[b*NS + c*64 + lane] = (unsigned short)r;
            const int cb = __popcll(bal);
            u += cb; kk += 64 - cb;
        }
        if (lane == 0) {
            int cp = (cnt + 63) & ~63;
            cntpad[b] = cp < 64 ? 64 : cp;
        }
#pragma unroll
        for (int c = 0; c < 16; ++c) {
            const int j = c*64 + lane;
            maskp[b*NS + j] = (j < cnt) ? 0.0f : -1.0e6f * LOG2E;
        }
        return;
    }
    size_t i = (size_t)blockIdx.x * 256 + threadIdx.x;
    if (i >= CVT_TOTAL) return;
    const float* src; bf16_t* dst;
    if      (i < 1*W4SZ)           { src = wq; dst = owq; }
    else if (i < 2*W4SZ)           { src = wk; dst = owk; i -= 1*W4SZ; }
    else if (i < 3*W4SZ)           { src = wv; dst = owv; i -= 2*W4SZ; }
    else if (i < 4*W4SZ)           { src = wo; dst = owo; i -= 3*W4SZ; }
    else if (i < 4*W4SZ + WBSZ)    { src = w1; dst = ow1; i -= 4*W4SZ; }
    else if (i < 4*W4SZ + 2*WBSZ)  { src = w2; dst = ow2; i -= 4*W4SZ + WBSZ; }
    else                           { src = x;  dst = ox;  i -= 4*W4SZ + 2*WBSZ; }
    const f4 v = ((const f4*)src)[i];
    bf4v o;
    o[0] = (bf16_t)v[0]; o[1] = (bf16_t)v[1]; o[2] = (bf16_t)v[2]; o[3] = (bf16_t)v[3];
    ((bf4v*)dst)[i] = o;
}

// ---------------------------------------------------------------------------
extern "C" void kernel_launch(void* const* d_in, const int* in_sizes, int n_in,
                              void* d_out, int out_size, void* d_ws, size_t ws_size,
                              hipStream_t stream)
{
    (void)in_sizes; (void)n_in; (void)out_size; (void)ws_size;
    const float* x   = (const float*)d_in[0];
    const int*   msk = (const int*)d_in[1];
    const float* WQ = (const float*)d_in[2];  const float* bQ  = (const float*)d_in[3];
    const float* WK = (const float*)d_in[4];  const float* bK  = (const float*)d_in[5];
    const float* WV = (const float*)d_in[6];  const float* bV  = (const float*)d_in[7];
    const float* WO = (const float*)d_in[8];  const float* bO  = (const float*)d_in[9];
    const float* W1 = (const float*)d_in[10]; const float* b1  = (const float*)d_in[11];
    const float* W2 = (const float*)d_in[12]; const float* b2  = (const float*)d_in[13];
    const float* g1 = (const float*)d_in[14]; const float* bt1 = (const float*)d_in[15];
    const float* g2 = (const float*)d_in[16]; const float* bt2 = (const float*)d_in[17];

    char* ws = (char*)d_ws;
    size_t off = 0;
    auto alloc = [&](size_t bytes) { char* p = ws + off; off += (bytes + 255) & ~(size_t)255; return p; };
    bf16_t* xb    = (bf16_t*)alloc((size_t)NROW*NE*2);
    bf16_t* Qb    = (bf16_t*)alloc((size_t)NROW*NE*2);
    bf16_t* Kb    = (bf16_t*)alloc((size_t)NROW*NE*2);
    bf16_t* Vtb   = (bf16_t*)alloc((size_t)NROW*NE*2);
    bf16_t* AOb   = (bf16_t*)alloc((size_t)NROW*NE*2);
    bf16_t* hb    = (bf16_t*)alloc((size_t)NROW*NHF*2);
    bf16_t* wqc   = (bf16_t*)alloc((size_t)NL*NE*NE*2);
    bf16_t* wkc   = (bf16_t*)alloc((size_t)NL*NE*NE*2);
    bf16_t* wvc   = (bf16_t*)alloc((size_t)NL*NE*NE*2);
    bf16_t* woc   = (bf16_t*)alloc((size_t)NL*NE*NE*2);
    bf16_t* w1c   = (bf16_t*)alloc((size_t)NL*NHF*NE*2);
    bf16_t* w2c   = (bf16_t*)alloc((size_t)NL*NE*NHF*2);
    float*  maskp = (float*) alloc((size_t)NB*NS*4);
    unsigned short* rankb = (unsigned short*)alloc((size_t)NB*NS*2);
    int*    cntp  = (int*)   alloc(NB*4);

    cvt_pack_k<<<dim3(CVT_BLOCKS + NB), dim3(256), 0, stream>>>(
        WQ, WK, WV, WO, W1, W2, x, wqc, wkc, wvc, woc, w1c, w2c, xb,
        msk, rankb, cntp, maskp);

    for (int l = 0; l < NL; ++l) {
        const bf16_t* wq  = wqc + (size_t)l*NE*NE;
        const bf16_t* wk  = wkc + (size_t)l*NE*NE;
        const bf16_t* wv  = wvc + (size_t)l*NE*NE;
        const bf16_t* wo  = woc + (size_t)l*NE*NE;
        const bf16_t* w1p = w1c + (size_t)l*NHF*NE;
        const bf16_t* w2p = w2c + (size_t)l*NE*NHF;
        const int last = (l == NL - 1);

        gemm_qkv_k<<<dim3(64, 8), dim3(256), 0, stream>>>(
            xb, wq, wk, wv, bQ + l*NE, bK + l*NE, bV + l*NE, Qb, Kb, Vtb, rankb);
        attn_k<<<dim3(64, 8), dim3(256), 0, stream>>>(Qb, Kb, Vtb, maskp, cntp, AOb);
        gemm_rmw_ln_k<<<dim3(256), dim3(512), 0, stream>>>(
            AOb, wo, bO + l*NE, xb, g1 + l*NE, bt1 + l*NE,
            nullptr, 0, NE);                              // xb = LN1(xb + O-proj)
        gemm256_k<1, 1><<<dim3(32, 8), dim3(512), 0, stream>>>(
            xb, w1p, b1 + l*NHF, hb, NHF, NE);
        gemm_bt_k<64, 0, 2><<<dim3(64, 8), dim3(256), 0, stream>>>(
            hb, w2p, b2 + l*NE, xb, NE, NHF);             // xb += FFN2
        ln_k<<<dim3(NROW/4), dim3(256), 0, stream>>>(
            xb, g2 + l*NE, bt2 + l*NE, (float*)d_out, last);
    }
}